// Round 6
// baseline (480.234 us; speedup 1.0000x reference)
//
#include <hip/hip_runtime.h>
#include <math.h>

#define KT 256
#define QA 8          // queries per sweepA block
#define SLICES 4      // point slices
#define QS 8          // queries per sample block
#define QBF 4         // queries per finalB block
#define CANDPQ 1024
#define NBUCKET 2048
#define TINY 256
#define TSAMP 8u
#define EPS_KNN 1e-12f
#define EPS_COS 1e-8f
#define MQ 8
// fallback (round-3) params
#define QB 2
#define CANDMAX 1024

__device__ __forceinline__ float wredf(float v) {
#pragma unroll
    for (int off = 32; off > 0; off >>= 1) v += __shfl_xor(v, off, 64);
    return v;
}
__device__ __forceinline__ unsigned int wredu(unsigned int v) {
#pragma unroll
    for (int off = 32; off > 0; off >>= 1) v += (unsigned int)__shfl_xor((int)v, off, 64);
    return v;
}

// Block-cooperative: smallest bucket b with cum(h[0..b]) >= T. Ends with sync.
template<int NB>
__device__ void scan_find(const unsigned int* h, unsigned int T,
                          int* out_b, unsigned int* out_total,
                          unsigned int* wtot, int tid)
{
    constexpr int CH = NB / KT;
    const int lane = tid & 63, wid = tid >> 6;
    const int base = tid * CH;
    unsigned int s = 0;
#pragma unroll
    for (int u = 0; u < CH; ++u) s += h[base + u];
    unsigned int incl = s;
#pragma unroll
    for (int d = 1; d < 64; d <<= 1) {
        unsigned int n = (unsigned int)__shfl_up((int)incl, d, 64);
        if (lane >= d) incl += n;
    }
    if (tid == 0) *out_b = -1;
    if (lane == 63) wtot[wid] = incl;
    __syncthreads();
    unsigned int offs = 0;
    for (int w = 0; w < wid; ++w) offs += wtot[w];
    const unsigned int total = wtot[0] + wtot[1] + wtot[2] + wtot[3];
    const unsigned int excl = offs + (incl - s);
    if (excl < T && T <= excl + s) {
        unsigned int c = excl;
        for (int u = 0; u < CH; ++u) {
            c += h[base + u];
            if (c >= T) { *out_b = base + u; break; }
        }
    }
    if (tid == 0) *out_total = total;
    __syncthreads();
}

// ---------------- pack: {x,y,z,|p|^2} ----------------
__global__ __launch_bounds__(256) void pack_kernel(
    const float* __restrict__ x0, const float* __restrict__ x1,
    float4* __restrict__ pts, int N0, int N)
{
    const int i = blockIdx.x * 256 + threadIdx.x;
    if (i >= N) return;
    float px, py, pz;
    if (i < N0) { px = x0[3 * i]; py = x0[3 * i + 1]; pz = x0[3 * i + 2]; }
    else { const int j = i - N0; px = x1[3 * j]; py = x1[3 * j + 1]; pz = x1[3 * j + 2]; }
    const float p2 = fmaf(px, px, fmaf(py, py, pz * pz));
    pts[i] = make_float4(px, py, pz, p2);
}

// ---------------- MLP (proven) ----------------
__global__ __launch_bounds__(512) void mlp_kernel(
    const float* __restrict__ z, const float* __restrict__ tp,
    const float* __restrict__ W1, const float* __restrict__ b1,
    const float* __restrict__ W2, const float* __restrict__ b2,
    const float* __restrict__ W3, const float* __restrict__ b3,
    float* __restrict__ xdot, int B)
{
    __shared__ float h1[MQ][512];
    __shared__ float red[8][MQ * 3];
    const int tid = threadIdx.x, lane = tid & 63, wid = tid >> 6;
    const int qbase = blockIdx.x * MQ;
    const float t = tp[0];

    for (int idx = tid; idx < MQ * 512; idx += 512) {
        const int q = idx >> 9, j = idx & 511;
        const int qid = qbase + q;
        float v = 0.f;
        if (qid < B) {
            const float a = z[qid * 6 + 0], b = z[qid * 6 + 1], c = z[qid * 6 + 2];
            v = fmaf(a, W1[j], fmaf(b, W1[512 + j], fmaf(c, W1[1024 + j], fmaf(t, W1[1536 + j], b1[j]))));
            v = fmaxf(v, 0.f);
        }
        h1[q][j] = v;
    }
    __syncthreads();

    const int col = wid * 64 + lane;
    float acc[MQ];
#pragma unroll
    for (int q = 0; q < MQ; ++q) acc[q] = b2[col];

    float w[4], wn[4];
#pragma unroll
    for (int u = 0; u < 4; ++u) w[u] = W2[u * 512 + col];
    for (int r = 0; r < 512; r += 4) {
        const int rn = r + 4;
        if (rn < 512) {
#pragma unroll
            for (int u = 0; u < 4; ++u) wn[u] = W2[(rn + u) * 512 + col];
        }
        float4 hv[MQ];
#pragma unroll
        for (int q = 0; q < MQ; ++q) hv[q] = *(const float4*)&h1[q][r];
#pragma unroll
        for (int q = 0; q < MQ; ++q) {
            acc[q] = fmaf(hv[q].x, w[0], acc[q]);
            acc[q] = fmaf(hv[q].y, w[1], acc[q]);
            acc[q] = fmaf(hv[q].z, w[2], acc[q]);
            acc[q] = fmaf(hv[q].w, w[3], acc[q]);
        }
#pragma unroll
        for (int u = 0; u < 4; ++u) w[u] = wn[u];
    }

    const float wc0 = W3[col * 3 + 0], wc1 = W3[col * 3 + 1], wc2 = W3[col * 3 + 2];
#pragma unroll
    for (int q = 0; q < MQ; ++q) {
        const float h = fmaxf(acc[q], 0.f);
        float p0 = h * wc0, p1 = h * wc1, p2 = h * wc2;
        p0 = wredf(p0); p1 = wredf(p1); p2 = wredf(p2);
        if (lane == 0) { red[wid][q * 3 + 0] = p0; red[wid][q * 3 + 1] = p1; red[wid][q * 3 + 2] = p2; }
    }
    __syncthreads();
    if (tid < MQ * 3) {
        const int q = tid / 3, d = tid % 3;
        float s = 0.f;
#pragma unroll
        for (int w8 = 0; w8 < 8; ++w8) s += red[w8][q * 3 + d];
        const int qid = qbase + q;
        if (qid < B) xdot[qid * 3 + d] = s + b3[d];
    }
}

// ---------------- sample: per-query cap + zero counters ----------------
__global__ __launch_bounds__(KT) void sample_kernel(
    const float* __restrict__ z, const float4* __restrict__ pts,
    float* __restrict__ capg, unsigned int* __restrict__ gcnt,
    int B, int N)
{
    __shared__ unsigned int hist[NBUCKET];
    __shared__ unsigned int wtot[4];
    __shared__ int s_b; __shared__ unsigned int s_tot;
    const int tid = threadIdx.x;
    const int q0 = blockIdx.x * QS;
    if (tid < QS && q0 + tid < B) gcnt[q0 + tid] = 0u;
    for (int u = 0; u < QS; ++u) {
        const int qid = q0 + u;
        for (int i = tid; i < NBUCKET; i += KT) hist[i] = 0u;
        __syncthreads();
        if (qid < B) {
            const float a = z[qid * 6 + 0], b = z[qid * 6 + 1], c = z[qid * 6 + 2];
            const float q2 = fmaf(a, a, fmaf(b, b, c * c));
            for (int s = tid; s < 2048; s += KT) {
                const int j = (int)(((long long)s * (long long)N) >> 11);
                const float4 P = pts[j];
                const float dt = fmaf(a, P.x, fmaf(b, P.y, c * P.z));
                float d2 = fmaf(-2.f, dt, q2 + P.w);
                d2 = fmaxf(d2, 0.f);
                int bu = (int)(__float_as_uint(d2) >> 20);
                bu = bu < (NBUCKET - 1) ? bu : (NBUCKET - 1);
                atomicAdd(&hist[bu], 1u);
            }
        }
        __syncthreads();
        scan_find<NBUCKET>(hist, TSAMP, &s_b, &s_tot, wtot, tid);
        if (tid == 0 && qid < B) {
            int bb = s_b; if (bb < 0) bb = NBUCKET - 1;
            const unsigned int ub = (unsigned int)(bb + 1);
            capg[qid] = (ub >= 2040u) ? 3.4e38f : __uint_as_float(ub << 20);
        }
        __syncthreads();
    }
}

// ---------------- sweepA: slice x query-group candidate collection ----------------
__global__ __launch_bounds__(KT) void sweepA_kernel(
    const float* __restrict__ z, const float4* __restrict__ pts,
    const float* __restrict__ capg, unsigned int* __restrict__ gcnt,
    float* __restrict__ gD, int* __restrict__ gI, int B, int N)
{
    const int tid = threadIdx.x;
    const int slice = blockIdx.x % SLICES;      // adjacent XCD-round-robin blocks share a slice
    const int qg = blockIdx.x / SLICES;
    const int q0 = qg * QA;
    float qx[QA], qy[QA], qz[QA], q2[QA], cp[QA];
#pragma unroll
    for (int u = 0; u < QA; ++u) {
        const int qid = q0 + u;
        float a = 0.f, b = 0.f, c = 0.f, cap = -1.f;
        if (qid < B) { a = z[qid * 6 + 0]; b = z[qid * 6 + 1]; c = z[qid * 6 + 2]; cap = capg[qid]; }
        qx[u] = a; qy[u] = b; qz[u] = c; q2[u] = fmaf(a, a, fmaf(b, b, c * c)); cp[u] = cap;
    }
    const int slen = (N + SLICES - 1) / SLICES;
    const int s0 = slice * slen;
    const int s1 = min(N, s0 + slen);
    int j = s0 + tid;
    bool v = j < s1;
    float4 P;
    if (v) P = pts[j];
    while (v) {
        const int jn = j + KT;
        const bool vn = jn < s1;
        float4 Pn;
        if (vn) Pn = pts[jn];
#pragma unroll
        for (int u = 0; u < QA; ++u) {
            const float dt = fmaf(qx[u], P.x, fmaf(qy[u], P.y, qz[u] * P.z));
            const float d2 = fmaf(-2.f, dt, q2[u] + P.w);
            if (d2 < cp[u]) {
                const unsigned int pos = atomicAdd(&gcnt[q0 + u], 1u);
                if (pos < (unsigned int)CANDPQ) {
                    gD[(size_t)(q0 + u) * CANDPQ + pos] = sqrtf(fmaxf(d2, 0.f));
                    gI[(size_t)(q0 + u) * CANDPQ + pos] = j;
                }
            }
        }
        j = jn; v = vn; P = Pn;
    }
}

// ---------------- finalB: exact k-th + weighted accumulation + metrics ----------------
__global__ __launch_bounds__(KT) void finalB_kernel(
    const float* __restrict__ z, const float4* __restrict__ pts,
    const float* __restrict__ v0, const float* __restrict__ v1,
    const float* __restrict__ xdot, const int* __restrict__ kp,
    const float* __restrict__ capg, const unsigned int* __restrict__ gcnt,
    const float* __restrict__ gD, const int* __restrict__ gI,
    float* __restrict__ out, int B, int N0, int N1)
{
    const int N = N0 + N1;
    const unsigned int K = (unsigned int)kp[0];
    __shared__ float candL[CANDPQ];
    __shared__ int   candIL[CANDPQ];
    __shared__ unsigned int fh[256];
    __shared__ float tinyD[TINY];
    __shared__ int   tinyI[TINY];
    __shared__ unsigned int tcnt, lcnt;
    __shared__ unsigned int wtot[4];
    __shared__ int s_b; __shared__ unsigned int s_tot;
    __shared__ float redbuf[4][4];
    __shared__ float s_hsel; __shared__ int s_isel;
    const int tid = threadIdx.x, lane = tid & 63, wid = tid >> 6;

    for (int u = 0; u < QBF; ++u) {
        const int qid = blockIdx.x * QBF + u;
        if (qid >= B) continue;                    // uniform across block
        const unsigned int cnt = gcnt[qid];
        const float capq = capg[qid];
        const float* Dp; const int* Ip; int m; float sc;
        const bool fast = (cnt >= K && cnt <= (unsigned int)CANDPQ);
        if (fast) {
            Dp = gD + (size_t)qid * CANDPQ; Ip = gI + (size_t)qid * CANDPQ;
            m = (int)cnt; sc = 256.f / sqrtf(capq);
        } else {
            // slow path: local re-collect with cap retry (rare / correctness net)
            const float a = z[qid * 6 + 0], b = z[qid * 6 + 1], c = z[qid * 6 + 2];
            const float q2 = fmaf(a, a, fmaf(b, b, c * c));
            float capL = capq;
            unsigned int cc = cnt;
            for (int att = 0; att < 6; ++att) {
                const unsigned int base = cc < 8u ? 8u : cc;
                capL *= __powf(384.f / (float)base, 0.6666667f);
                if (tid == 0) lcnt = 0u;
                __syncthreads();
                for (int jj = tid; jj < N; jj += KT) {
                    const float4 P = pts[jj];
                    const float dt = fmaf(a, P.x, fmaf(b, P.y, c * P.z));
                    const float d2 = fmaf(-2.f, dt, q2 + P.w);
                    if (d2 < capL) {
                        const unsigned int pos = atomicAdd(&lcnt, 1u);
                        if (pos < (unsigned int)CANDPQ) { candL[pos] = sqrtf(fmaxf(d2, 0.f)); candIL[pos] = jj; }
                    }
                }
                __syncthreads();
                cc = lcnt;
                if (cc >= K && cc <= (unsigned int)CANDPQ) break;
            }
            Dp = candL; Ip = candIL;
            m = (int)(cc <= (unsigned int)CANDPQ ? cc : (unsigned int)CANDPQ);
            sc = 256.f / sqrtf(capL);
        }
        // select k-th via 256-bin hist + tiny lexicographic rank
        fh[tid] = 0u;
        __syncthreads();
        for (int i = tid; i < m; i += KT) {
            int bb = (int)(Dp[i] * sc); bb = bb < 255 ? bb : 255;
            atomicAdd(&fh[bb], 1u);
        }
        __syncthreads();
        scan_find<256>(fh, K, &s_b, &s_tot, wtot, tid);
        const int bsel = s_b < 0 ? 255 : s_b;
        unsigned int vv = (tid < bsel) ? fh[tid] : 0u;
        vv = wredu(vv);
        if (lane == 0) wtot[wid] = vv;
        if (tid == 0) { tcnt = 0u; s_hsel = 3.4e38f; s_isel = 0x7fffffff; }
        __syncthreads();
        const unsigned int Cb = wtot[0] + wtot[1] + wtot[2] + wtot[3];
        for (int i = tid; i < m; i += KT) {
            int bb = (int)(Dp[i] * sc); bb = bb < 255 ? bb : 255;
            if (bb == bsel) {
                const unsigned int p = atomicAdd(&tcnt, 1u);
                if (p < (unsigned int)TINY) { tinyD[p] = Dp[i]; tinyI[p] = Ip[i]; }
            }
        }
        __syncthreads();
        const int c2 = (int)tcnt;
        const int need = (int)K - 1 - (int)Cb;
        if (c2 <= TINY) {
            for (int i = tid; i < c2; i += KT) {
                const float di = tinyD[i]; const int ii = tinyI[i];
                int r = 0;
                for (int j2 = 0; j2 < c2; ++j2) {
                    const float dj = tinyD[j2];
                    if (dj < di || (dj == di && tinyI[j2] < ii)) ++r;
                }
                if (r == need) { s_hsel = di; s_isel = ii; }
            }
        } else {
            for (int i = tid; i < m; i += KT) {
                const float di = Dp[i]; const int ii = Ip[i];
                int r = 0;
                for (int j2 = 0; j2 < m; ++j2) {
                    const float dj = Dp[j2];
                    if (dj < di || (dj == di && Ip[j2] < ii)) ++r;
                }
                if (r == (int)K - 1) { s_hsel = di; s_isel = ii; }
            }
        }
        __syncthreads();
        const float hS = s_hsel; const int iS = s_isel;
        const float hcl = fmaxf(hS, EPS_KNN);
        const float inv2h2 = 1.f / (2.f * hcl * hcl);
        float ws = 0.f, ax = 0.f, ay = 0.f, az = 0.f;
        for (int i = tid; i < m; i += KT) {
            const float s = Dp[i]; const int jj = Ip[i];
            if (s < hS || (s == hS && jj <= iS)) {
                const float w = expf(-(s * s) * inv2h2);
                const float* vp = (jj < N0) ? (v0 + 3 * (size_t)jj) : (v1 + 3 * (size_t)(jj - N0));
                ws += w; ax = fmaf(w, vp[0], ax); ay = fmaf(w, vp[1], ay); az = fmaf(w, vp[2], az);
            }
        }
        ws = wredf(ws); ax = wredf(ax); ay = wredf(ay); az = wredf(az);
        if (lane == 0) { redbuf[wid][0] = ws; redbuf[wid][1] = ax; redbuf[wid][2] = ay; redbuf[wid][3] = az; }
        __syncthreads();
        if (tid == 0) {
            const float wsum = redbuf[0][0] + redbuf[1][0] + redbuf[2][0] + redbuf[3][0];
            const float axs  = redbuf[0][1] + redbuf[1][1] + redbuf[2][1] + redbuf[3][1];
            const float ays  = redbuf[0][2] + redbuf[1][2] + redbuf[2][2] + redbuf[3][2];
            const float azs  = redbuf[0][3] + redbuf[1][3] + redbuf[2][3] + redbuf[3][3];
            const float inv = 1.f / (wsum + EPS_KNN);
            const float ux = axs * inv, uy = ays * inv, uz = azs * inv;
            const float d0 = xdot[qid * 3 + 0], d1 = xdot[qid * 3 + 1], d2v = xdot[qid * 3 + 2];
            const float nu = fmaxf(sqrtf(ux * ux + uy * uy + uz * uz), EPS_COS);
            const float nd = fmaxf(sqrtf(d0 * d0 + d1 * d1 + d2v * d2v), EPS_COS);
            const float cs = 1.f - (ux * d0 + uy * d1 + uz * d2v) / (nu * nd);
            const float ex = ux - d0, ey = uy - d1, ez = uz - d2v;
            const float l2 = ex * ex + ey * ey + ez * ez;
            out[qid * 6 + 0] = d0; out[qid * 6 + 1] = d1; out[qid * 6 + 2] = d2v;
            out[qid * 6 + 3] = cs; out[qid * 6 + 4] = cs; out[qid * 6 + 5] = l2;
        }
        __syncthreads();
    }
}

// ---------------- fallback: round-3 monolithic knn (proven, used if ws too small) ----
__global__ __launch_bounds__(KT) void knn_fallback(
    const float* __restrict__ z,
    const float* __restrict__ x0, const float* __restrict__ x1,
    const float* __restrict__ v0, const float* __restrict__ v1,
    const float* __restrict__ xdot, const int* __restrict__ kp,
    float* __restrict__ out, int B, int N0, int N1)
{
    const int N = N0 + N1;
    const unsigned int K = (unsigned int)kp[0];
    __shared__ unsigned int hist[QB][NBUCKET];
    float (*candD)[CANDMAX] = (float (*)[CANDMAX])&hist[0][0];
    int   (*candI)[CANDMAX] = (int (*)[CANDMAX])((char*)&hist[0][0] + sizeof(float) * QB * CANDMAX);
    __shared__ unsigned int fh[256];
    __shared__ float tinyD[TINY];
    __shared__ int   tinyI[TINY];
    __shared__ unsigned int tcnt;
    __shared__ unsigned int candCnt[QB];
    __shared__ float capv[QB];
    __shared__ float hselv[QB];
    __shared__ int   iselv[QB];
    __shared__ int   doneQ[QB];
    __shared__ int   anyleft;
    __shared__ unsigned int wtot[4];
    __shared__ int s_b;
    __shared__ unsigned int s_tot;
    __shared__ float qsh[QB][4];
    __shared__ float redbuf[4][QB * 4];
    const int tid = threadIdx.x, lane = tid & 63, wid = tid >> 6;
    const int qbase = blockIdx.x * QB;

    if (tid < QB) {
        const int qid = qbase + tid;
        float a = 0.f, b = 0.f, c = 0.f;
        if (qid < B) { a = z[qid * 6 + 0]; b = z[qid * 6 + 1]; c = z[qid * 6 + 2]; }
        qsh[tid][0] = a; qsh[tid][1] = b; qsh[tid][2] = c;
        qsh[tid][3] = fmaf(a, a, fmaf(b, b, c * c));
    }
    for (int i = tid; i < QB * NBUCKET; i += KT) (&hist[0][0])[i] = 0u;
    __syncthreads();
    float qx[QB], qy[QB], qz[QB], q2[QB];
#pragma unroll
    for (int q = 0; q < QB; ++q) { qx[q] = qsh[q][0]; qy[q] = qsh[q][1]; qz[q] = qsh[q][2]; q2[q] = qsh[q][3]; }

    auto doPoint = [&](float px, float py, float pz, int idx, auto&& fn) {
        const float p2 = fmaf(px, px, fmaf(py, py, pz * pz));
#pragma unroll
        for (int q = 0; q < QB; ++q) {
            const float dt = fmaf(qx[q], px, fmaf(qy[q], py, qz[q] * pz));
            const float d2 = fmaf(-2.f, dt, q2[q] + p2);
            fn(q, idx, d2);
        }
    };
    auto sweepAll = [&](auto&& fn) {
        const int G0 = N0 >> 2;
        for (int g = tid; g < G0; g += KT) {
            const float4* bp = (const float4*)(x0 + 12 * (size_t)g);
            const float4 A = bp[0], Bv = bp[1], C = bp[2];
            doPoint(A.x, A.y, A.z, 4 * g + 0, fn);
            doPoint(A.w, Bv.x, Bv.y, 4 * g + 1, fn);
            doPoint(Bv.z, Bv.w, C.x, 4 * g + 2, fn);
            doPoint(C.y, C.z, C.w, 4 * g + 3, fn);
        }
        for (int j = (G0 << 2) + tid; j < N0; j += KT)
            doPoint(x0[3 * j], x0[3 * j + 1], x0[3 * j + 2], j, fn);
        const int G1 = N1 >> 2;
        for (int g = tid; g < G1; g += KT) {
            const float4* bp = (const float4*)(x1 + 12 * (size_t)g);
            const float4 A = bp[0], Bv = bp[1], C = bp[2];
            doPoint(A.x, A.y, A.z, N0 + 4 * g + 0, fn);
            doPoint(A.w, Bv.x, Bv.y, N0 + 4 * g + 1, fn);
            doPoint(Bv.z, Bv.w, C.x, N0 + 4 * g + 2, fn);
            doPoint(C.y, C.z, C.w, N0 + 4 * g + 3, fn);
        }
        for (int j = (G1 << 2) + tid; j < N1; j += KT)
            doPoint(x1[3 * j], x1[3 * j + 1], x1[3 * j + 2], N0 + j, fn);
    };

    for (int s = tid; s < 2048; s += KT) {
        const int j = (int)(((long long)s * (long long)N) >> 11);
        float px, py, pz;
        if (j < N0) { px = x0[3 * j]; py = x0[3 * j + 1]; pz = x0[3 * j + 2]; }
        else { const int j2 = j - N0; px = x1[3 * j2]; py = x1[3 * j2 + 1]; pz = x1[3 * j2 + 2]; }
        const float p2 = fmaf(px, px, fmaf(py, py, pz * pz));
#pragma unroll
        for (int q = 0; q < QB; ++q) {
            const float dt = fmaf(qx[q], px, fmaf(qy[q], py, qz[q] * pz));
            float d2 = fmaf(-2.f, dt, q2[q] + p2);
            d2 = fmaxf(d2, 0.f);
            int bu = (int)(__float_as_uint(d2) >> 20);
            bu = bu < (NBUCKET - 1) ? bu : (NBUCKET - 1);
            atomicAdd(&hist[q][bu], 1u);
        }
    }
    __syncthreads();
    for (int q = 0; q < QB; ++q) {
        scan_find<NBUCKET>(&hist[q][0], TSAMP, &s_b, &s_tot, wtot, tid);
        if (tid == 0) {
            int b = s_b; if (b < 0) b = NBUCKET - 1;
            const unsigned int ub = (unsigned int)(b + 1);
            const float cap = (ub >= 2040u) ? 3.4e38f : __uint_as_float(ub << 20);
            capv[q] = (qbase + q < B) ? cap : -1.f;
            doneQ[q] = (qbase + q < B) ? 0 : 1;
        }
        __syncthreads();
    }
    for (int attempt = 0; attempt < 4; ++attempt) {
        if (tid == 0) anyleft = 0;
        if (tid < QB && !doneQ[tid]) candCnt[tid] = 0u;
        __syncthreads();
        float rcap[QB];
#pragma unroll
        for (int q = 0; q < QB; ++q) rcap[q] = doneQ[q] ? -1.f : capv[q];
        sweepAll([&](int q, int j, float d2) {
            if (d2 < rcap[q]) {
                const unsigned int pos = atomicAdd(&candCnt[q], 1u);
                if (pos < (unsigned int)CANDMAX) { candD[q][pos] = sqrtf(fmaxf(d2, 0.f)); candI[q][pos] = j; }
            }
        });
        __syncthreads();
        if (tid < QB && !doneQ[tid]) {
            const unsigned int c = candCnt[tid];
            if (c >= K && c <= (unsigned int)CANDMAX) doneQ[tid] = 1;
            else {
                const unsigned int cc = c < 8u ? 8u : c;
                capv[tid] *= __powf(384.f / (float)cc, 0.6666667f);
                anyleft = 1;
            }
        }
        __syncthreads();
        if (!anyleft) break;
    }
    for (int q = 0; q < QB; ++q) {
        if (qbase + q >= B) continue;
        const unsigned int cnt = candCnt[q];
        const int m = (int)(cnt < (unsigned int)CANDMAX ? cnt : (unsigned int)CANDMAX);
        fh[tid] = 0u;
        __syncthreads();
        const float sc = 256.f / sqrtf(capv[q]);
        for (int i = tid; i < m; i += KT) {
            int b = (int)(candD[q][i] * sc); b = b < 255 ? b : 255;
            atomicAdd(&fh[b], 1u);
        }
        __syncthreads();
        scan_find<256>(fh, K, &s_b, &s_tot, wtot, tid);
        const int bsel = s_b < 0 ? 255 : s_b;
        unsigned int v = (tid < bsel) ? fh[tid] : 0u;
        v = wredu(v);
        if (lane == 0) wtot[wid] = v;
        if (tid == 0) tcnt = 0u;
        __syncthreads();
        const unsigned int Cb = wtot[0] + wtot[1] + wtot[2] + wtot[3];
        for (int i = tid; i < m; i += KT) {
            int b = (int)(candD[q][i] * sc); b = b < 255 ? b : 255;
            if (b == bsel) {
                const unsigned int p = atomicAdd(&tcnt, 1u);
                if (p < (unsigned int)TINY) { tinyD[p] = candD[q][i]; tinyI[p] = candI[q][i]; }
            }
        }
        __syncthreads();
        const int c2 = (int)tcnt;
        const int need = (int)K - 1 - (int)Cb;
        if (c2 <= TINY) {
            for (int i = tid; i < c2; i += KT) {
                const float di = tinyD[i]; const int ii = tinyI[i];
                int r = 0;
                for (int j2 = 0; j2 < c2; ++j2) {
                    const float dj = tinyD[j2];
                    if (dj < di || (dj == di && tinyI[j2] < ii)) ++r;
                }
                if (r == need) { hselv[q] = di; iselv[q] = ii; }
            }
        } else {
            for (int i = tid; i < m; i += KT) {
                const float di = candD[q][i]; const int ii = candI[q][i];
                int r = 0;
                for (int j2 = 0; j2 < m; ++j2) {
                    const float dj = candD[q][j2];
                    if (dj < di || (dj == di && candI[q][j2] < ii)) ++r;
                }
                if (r == (int)K - 1) { hselv[q] = di; iselv[q] = ii; }
            }
        }
        __syncthreads();
    }
    for (int q = 0; q < QB; ++q) {
        if (qbase + q >= B) continue;
        const float hS = hselv[q];
        const int iS = iselv[q];
        const float hcl = fmaxf(hS, EPS_KNN);
        const float inv2h2 = 1.f / (2.f * hcl * hcl);
        const unsigned int cnt = candCnt[q];
        const int m = (int)(cnt < (unsigned int)CANDMAX ? cnt : (unsigned int)CANDMAX);
        float ws = 0.f, ax = 0.f, ay = 0.f, az = 0.f;
        for (int i = tid; i < m; i += KT) {
            const float s = candD[q][i];
            const int j = candI[q][i];
            if (s < hS || (s == hS && j <= iS)) {
                const float w = expf(-(s * s) * inv2h2);
                const float* vp = (j < N0) ? (v0 + 3 * (size_t)j) : (v1 + 3 * (size_t)(j - N0));
                ws += w; ax = fmaf(w, vp[0], ax); ay = fmaf(w, vp[1], ay); az = fmaf(w, vp[2], az);
            }
        }
        ws = wredf(ws); ax = wredf(ax); ay = wredf(ay); az = wredf(az);
        if (lane == 0) {
            redbuf[wid][q * 4 + 0] = ws; redbuf[wid][q * 4 + 1] = ax;
            redbuf[wid][q * 4 + 2] = ay; redbuf[wid][q * 4 + 3] = az;
        }
    }
    __syncthreads();
    if (tid < QB) {
        const int q = tid, qid = qbase + q;
        if (qid < B) {
            const float ws = redbuf[0][q*4+0] + redbuf[1][q*4+0] + redbuf[2][q*4+0] + redbuf[3][q*4+0];
            const float ax = redbuf[0][q*4+1] + redbuf[1][q*4+1] + redbuf[2][q*4+1] + redbuf[3][q*4+1];
            const float ay = redbuf[0][q*4+2] + redbuf[1][q*4+2] + redbuf[2][q*4+2] + redbuf[3][q*4+2];
            const float az = redbuf[0][q*4+3] + redbuf[1][q*4+3] + redbuf[2][q*4+3] + redbuf[3][q*4+3];
            const float inv = 1.f / (ws + EPS_KNN);
            const float ux = ax * inv, uy = ay * inv, uz = az * inv;
            const float d0 = xdot[qid * 3 + 0], d1 = xdot[qid * 3 + 1], d2v = xdot[qid * 3 + 2];
            const float nu = fmaxf(sqrtf(ux * ux + uy * uy + uz * uz), EPS_COS);
            const float nd = fmaxf(sqrtf(d0 * d0 + d1 * d1 + d2v * d2v), EPS_COS);
            const float cs = 1.f - (ux * d0 + uy * d1 + uz * d2v) / (nu * nd);
            const float ex = ux - d0, ey = uy - d1, ez = uz - d2v;
            const float l2 = ex * ex + ey * ey + ez * ez;
            out[qid * 6 + 0] = d0; out[qid * 6 + 1] = d1; out[qid * 6 + 2] = d2v;
            out[qid * 6 + 3] = cs; out[qid * 6 + 4] = cs; out[qid * 6 + 5] = l2;
        }
    }
}

extern "C" void kernel_launch(void* const* d_in, const int* in_sizes, int n_in,
                              void* d_out, int out_size, void* d_ws, size_t ws_size,
                              hipStream_t stream)
{
    const float* z  = (const float*)d_in[0];
    const float* tp = (const float*)d_in[1];
    const float* x0 = (const float*)d_in[2];
    const float* x1 = (const float*)d_in[3];
    const float* v0 = (const float*)d_in[4];
    const float* v1 = (const float*)d_in[5];
    const float* W1 = (const float*)d_in[6];
    const float* b1 = (const float*)d_in[7];
    const float* W2 = (const float*)d_in[8];
    const float* b2 = (const float*)d_in[9];
    const float* W3 = (const float*)d_in[10];
    const float* b3 = (const float*)d_in[11];
    const int*   kp = (const int*)d_in[12];
    float* outp = (float*)d_out;
    const int B  = in_sizes[0] / 6;
    const int N0 = in_sizes[2] / 3;
    const int N1 = in_sizes[3] / 3;
    const int N  = N0 + N1;

    // ws layout
    size_t off = 0;
    auto alloc = [&](size_t bytes) { size_t o = off; off = (off + bytes + 255) & ~(size_t)255; return o; };
    const size_t o_xdot = alloc((size_t)B * 3 * sizeof(float));
    const size_t o_pts  = alloc((size_t)N * sizeof(float4));
    const size_t o_cap  = alloc((size_t)B * sizeof(float));
    const size_t o_cnt  = alloc((size_t)B * sizeof(unsigned int));
    const size_t o_gD   = alloc((size_t)B * CANDPQ * sizeof(float));
    const size_t o_gI   = alloc((size_t)B * CANDPQ * sizeof(int));
    const bool split = ws_size >= off;

    float* xdot = (float*)((char*)d_ws + o_xdot);

    hipLaunchKernelGGL(mlp_kernel, dim3((B + MQ - 1) / MQ), dim3(512), 0, stream,
                       z, tp, W1, b1, W2, b2, W3, b3, xdot, B);
    if (split) {
        float4* pts = (float4*)((char*)d_ws + o_pts);
        float* capg = (float*)((char*)d_ws + o_cap);
        unsigned int* gcnt = (unsigned int*)((char*)d_ws + o_cnt);
        float* gD = (float*)((char*)d_ws + o_gD);
        int*   gI = (int*)((char*)d_ws + o_gI);
        const int QG = (B + QA - 1) / QA;
        hipLaunchKernelGGL(pack_kernel, dim3((N + 255) / 256), dim3(256), 0, stream,
                           x0, x1, pts, N0, N);
        hipLaunchKernelGGL(sample_kernel, dim3((B + QS - 1) / QS), dim3(KT), 0, stream,
                           z, pts, capg, gcnt, B, N);
        hipLaunchKernelGGL(sweepA_kernel, dim3(QG * SLICES), dim3(KT), 0, stream,
                           z, pts, capg, gcnt, gD, gI, B, N);
        hipLaunchKernelGGL(finalB_kernel, dim3((B + QBF - 1) / QBF), dim3(KT), 0, stream,
                           z, pts, v0, v1, xdot, kp, capg, gcnt, gD, gI, outp, B, N0, N1);
    } else {
        hipLaunchKernelGGL(knn_fallback, dim3((B + QB - 1) / QB), dim3(KT), 0, stream,
                           z, x0, x1, v0, v1, xdot, kp, outp, B, N0, N1);
    }
}

// Round 7
// 378.221 us; speedup vs baseline: 1.2697x; 1.2697x over previous
//
#include <hip/hip_runtime.h>
#include <math.h>

#define KT 256
#define QA 8          // queries per sweepA block
#define SLICES 4      // point slices
#define LCAP 384      // LDS candidate capacity per query per block
#define QBF 4         // queries per finalB block
#define CANDPQ 1024
#define NBUCKET 2048
#define TINY 256
#define TSAMP 8u
#define EPS_KNN 1e-12f
#define EPS_COS 1e-8f
#define MQ 8
// fallback (round-3) params
#define QB 2
#define CANDMAX 1024

__device__ __forceinline__ float wredf(float v) {
#pragma unroll
    for (int off = 32; off > 0; off >>= 1) v += __shfl_xor(v, off, 64);
    return v;
}
__device__ __forceinline__ unsigned int wredu(unsigned int v) {
#pragma unroll
    for (int off = 32; off > 0; off >>= 1) v += (unsigned int)__shfl_xor((int)v, off, 64);
    return v;
}

// Block-cooperative: smallest bucket b with cum(h[0..b]) >= T. Ends with sync.
template<int NB>
__device__ void scan_find(const unsigned int* h, unsigned int T,
                          int* out_b, unsigned int* out_total,
                          unsigned int* wtot, int tid)
{
    constexpr int CH = NB / KT;
    const int lane = tid & 63, wid = tid >> 6;
    const int base = tid * CH;
    unsigned int s = 0;
#pragma unroll
    for (int u = 0; u < CH; ++u) s += h[base + u];
    unsigned int incl = s;
#pragma unroll
    for (int d = 1; d < 64; d <<= 1) {
        unsigned int n = (unsigned int)__shfl_up((int)incl, d, 64);
        if (lane >= d) incl += n;
    }
    if (tid == 0) *out_b = -1;
    if (lane == 63) wtot[wid] = incl;
    __syncthreads();
    unsigned int offs = 0;
    for (int w = 0; w < wid; ++w) offs += wtot[w];
    const unsigned int total = wtot[0] + wtot[1] + wtot[2] + wtot[3];
    const unsigned int excl = offs + (incl - s);
    if (excl < T && T <= excl + s) {
        unsigned int c = excl;
        for (int u = 0; u < CH; ++u) {
            c += h[base + u];
            if (c >= T) { *out_b = base + u; break; }
        }
    }
    if (tid == 0) *out_total = total;
    __syncthreads();
}

// ---------------- pack: {x,y,z,|p|^2} ----------------
__global__ __launch_bounds__(256) void pack_kernel(
    const float* __restrict__ x0, const float* __restrict__ x1,
    float4* __restrict__ pts, int N0, int N)
{
    const int i = blockIdx.x * 256 + threadIdx.x;
    if (i >= N) return;
    float px, py, pz;
    if (i < N0) { px = x0[3 * i]; py = x0[3 * i + 1]; pz = x0[3 * i + 2]; }
    else { const int j = i - N0; px = x1[3 * j]; py = x1[3 * j + 1]; pz = x1[3 * j + 2]; }
    const float p2 = fmaf(px, px, fmaf(py, py, pz * pz));
    pts[i] = make_float4(px, py, pz, p2);
}

// ---------------- MLP (proven) ----------------
__global__ __launch_bounds__(512) void mlp_kernel(
    const float* __restrict__ z, const float* __restrict__ tp,
    const float* __restrict__ W1, const float* __restrict__ b1,
    const float* __restrict__ W2, const float* __restrict__ b2,
    const float* __restrict__ W3, const float* __restrict__ b3,
    float* __restrict__ xdot, int B)
{
    __shared__ float h1[MQ][512];
    __shared__ float red[8][MQ * 3];
    const int tid = threadIdx.x, lane = tid & 63, wid = tid >> 6;
    const int qbase = blockIdx.x * MQ;
    const float t = tp[0];

    for (int idx = tid; idx < MQ * 512; idx += 512) {
        const int q = idx >> 9, j = idx & 511;
        const int qid = qbase + q;
        float v = 0.f;
        if (qid < B) {
            const float a = z[qid * 6 + 0], b = z[qid * 6 + 1], c = z[qid * 6 + 2];
            v = fmaf(a, W1[j], fmaf(b, W1[512 + j], fmaf(c, W1[1024 + j], fmaf(t, W1[1536 + j], b1[j]))));
            v = fmaxf(v, 0.f);
        }
        h1[q][j] = v;
    }
    __syncthreads();

    const int col = wid * 64 + lane;
    float acc[MQ];
#pragma unroll
    for (int q = 0; q < MQ; ++q) acc[q] = b2[col];

    float w[4], wn[4];
#pragma unroll
    for (int u = 0; u < 4; ++u) w[u] = W2[u * 512 + col];
    for (int r = 0; r < 512; r += 4) {
        const int rn = r + 4;
        if (rn < 512) {
#pragma unroll
            for (int u = 0; u < 4; ++u) wn[u] = W2[(rn + u) * 512 + col];
        }
        float4 hv[MQ];
#pragma unroll
        for (int q = 0; q < MQ; ++q) hv[q] = *(const float4*)&h1[q][r];
#pragma unroll
        for (int q = 0; q < MQ; ++q) {
            acc[q] = fmaf(hv[q].x, w[0], acc[q]);
            acc[q] = fmaf(hv[q].y, w[1], acc[q]);
            acc[q] = fmaf(hv[q].z, w[2], acc[q]);
            acc[q] = fmaf(hv[q].w, w[3], acc[q]);
        }
#pragma unroll
        for (int u = 0; u < 4; ++u) w[u] = wn[u];
    }

    const float wc0 = W3[col * 3 + 0], wc1 = W3[col * 3 + 1], wc2 = W3[col * 3 + 2];
#pragma unroll
    for (int q = 0; q < MQ; ++q) {
        const float h = fmaxf(acc[q], 0.f);
        float p0 = h * wc0, p1 = h * wc1, p2 = h * wc2;
        p0 = wredf(p0); p1 = wredf(p1); p2 = wredf(p2);
        if (lane == 0) { red[wid][q * 3 + 0] = p0; red[wid][q * 3 + 1] = p1; red[wid][q * 3 + 2] = p2; }
    }
    __syncthreads();
    if (tid < MQ * 3) {
        const int q = tid / 3, d = tid % 3;
        float s = 0.f;
#pragma unroll
        for (int w8 = 0; w8 < 8; ++w8) s += red[w8][q * 3 + d];
        const int qid = qbase + q;
        if (qid < B) xdot[qid * 3 + d] = s + b3[d];
    }
}

// ---------------- sample: 1 query/block, cap + zero counter ----------------
__global__ __launch_bounds__(KT) void sample_kernel(
    const float* __restrict__ z, const float4* __restrict__ pts,
    float* __restrict__ capg, unsigned int* __restrict__ gcnt,
    int B, int N)
{
    __shared__ unsigned int hist[NBUCKET];
    __shared__ unsigned int wtot[4];
    __shared__ int s_b; __shared__ unsigned int s_tot;
    const int tid = threadIdx.x, qid = blockIdx.x;
    if (qid >= B) return;
    for (int i = tid; i < NBUCKET; i += KT) hist[i] = 0u;
    __syncthreads();
    const float a = z[qid * 6 + 0], b = z[qid * 6 + 1], c = z[qid * 6 + 2];
    const float q2 = fmaf(a, a, fmaf(b, b, c * c));
    for (int s = tid; s < 2048; s += KT) {
        const int j = (int)(((long long)s * (long long)N) >> 11);
        const float4 P = pts[j];
        const float dt = fmaf(a, P.x, fmaf(b, P.y, c * P.z));
        float d2 = fmaf(-2.f, dt, q2 + P.w);
        d2 = fmaxf(d2, 0.f);
        int bu = (int)(__float_as_uint(d2) >> 20);
        bu = bu < (NBUCKET - 1) ? bu : (NBUCKET - 1);
        atomicAdd(&hist[bu], 1u);
    }
    __syncthreads();
    scan_find<NBUCKET>(hist, TSAMP, &s_b, &s_tot, wtot, tid);
    if (tid == 0) {
        int bb = s_b; if (bb < 0) bb = NBUCKET - 1;
        const unsigned int ub = (unsigned int)(bb + 1);
        capg[qid] = (ub >= 2040u) ? 3.4e38f : __uint_as_float(ub << 20);
        gcnt[qid] = 0u;
    }
}

// ---------------- sweepA: LDS-staged candidate collection ----------------
__global__ __launch_bounds__(KT) void sweepA_kernel(
    const float* __restrict__ z, const float4* __restrict__ pts,
    const float* __restrict__ capg, unsigned int* __restrict__ gcnt,
    float* __restrict__ gD, int* __restrict__ gI, int B, int N)
{
    __shared__ float ldsD[QA][LCAP];
    __shared__ int   ldsI[QA][LCAP];
    __shared__ unsigned int lcnt[QA];
    __shared__ unsigned int gbase[QA];
    const int tid = threadIdx.x;
    const int slice = blockIdx.x & (SLICES - 1);
    const int qg = blockIdx.x / SLICES;
    const int q0 = qg * QA;
    if (tid < QA) lcnt[tid] = 0u;
    float qx[QA], qy[QA], qz[QA], qw[QA], cp[QA];
#pragma unroll
    for (int u = 0; u < QA; ++u) {
        const int qid = q0 + u;
        float a = 0.f, b = 0.f, c = 0.f, cap = -1.f;
        if (qid < B) { a = z[qid * 6 + 0]; b = z[qid * 6 + 1]; c = z[qid * 6 + 2]; cap = capg[qid]; }
        qx[u] = a; qy[u] = b; qz[u] = c; qw[u] = fmaf(a, a, fmaf(b, b, c * c)); cp[u] = cap;
    }
    __syncthreads();
    const int slen = (N + SLICES - 1) / SLICES;
    const int s0 = slice * slen;
    const int s1 = min(N, s0 + slen);
    int j = s0 + tid;
    bool valid = j < s1;
    float4 P;
    if (valid) P = pts[j];
    while (valid) {
        const int jn = j + KT;
        const bool vn = jn < s1;
        float4 Pn;
        if (vn) Pn = pts[jn];
#pragma unroll
        for (int u = 0; u < QA; ++u) {
            const float dt = fmaf(qx[u], P.x, fmaf(qy[u], P.y, qz[u] * P.z));
            const float d2 = fmaf(-2.f, dt, qw[u] + P.w);
            if (d2 < cp[u]) {
                const unsigned int pos = atomicAdd(&lcnt[u], 1u);
                if (pos < (unsigned int)LCAP) {
                    ldsD[u][pos] = sqrtf(fmaxf(d2, 0.f));
                    ldsI[u][pos] = j;
                }
            }
        }
        j = jn; valid = vn; P = Pn;
    }
    __syncthreads();
    if (tid < QA) {
        const unsigned int c = lcnt[tid];
        const unsigned int clip = c < (unsigned int)LCAP ? c : (unsigned int)LCAP;
        const unsigned int add = clip + (c > (unsigned int)LCAP ? 1000000u : 0u);
        gbase[tid] = (q0 + tid < B) ? atomicAdd(&gcnt[q0 + tid], add) : 0u;
        lcnt[tid] = clip;
    }
    __syncthreads();
    for (int u = 0; u < QA; ++u) {
        const int qid = q0 + u;
        if (qid >= B) continue;
        const unsigned int clip = lcnt[u];
        const unsigned int base = gbase[u];
        for (unsigned int i = tid; i < clip; i += KT) {
            const unsigned int off = base + i;
            if (off < (unsigned int)CANDPQ) {
                gD[(size_t)qid * CANDPQ + off] = ldsD[u][i];
                gI[(size_t)qid * CANDPQ + off] = ldsI[u][i];
            }
        }
    }
}

// ---------------- finalB: exact k-th + weighted accumulation + metrics ----------------
__global__ __launch_bounds__(KT) void finalB_kernel(
    const float* __restrict__ z, const float4* __restrict__ pts,
    const float* __restrict__ v0, const float* __restrict__ v1,
    const float* __restrict__ xdot, const int* __restrict__ kp,
    const float* __restrict__ capg, const unsigned int* __restrict__ gcnt,
    const float* __restrict__ gD, const int* __restrict__ gI,
    float* __restrict__ out, int B, int N0, int N1)
{
    const int N = N0 + N1;
    const unsigned int K = (unsigned int)kp[0];
    __shared__ float candL[CANDPQ];
    __shared__ int   candIL[CANDPQ];
    __shared__ unsigned int fh[256];
    __shared__ float tinyD[TINY];
    __shared__ int   tinyI[TINY];
    __shared__ unsigned int tcnt, lcnt;
    __shared__ unsigned int wtot[4];
    __shared__ int s_b; __shared__ unsigned int s_tot;
    __shared__ float redbuf[4][4];
    __shared__ float s_hsel; __shared__ int s_isel;
    const int tid = threadIdx.x, lane = tid & 63, wid = tid >> 6;

    for (int u = 0; u < QBF; ++u) {
        const int qid = blockIdx.x * QBF + u;
        if (qid >= B) continue;                    // uniform across block
        const unsigned int cnt = gcnt[qid];
        const float capq = capg[qid];
        const float* Dp; const int* Ip; int m; float sc;
        const bool fast = (cnt >= K && cnt <= (unsigned int)CANDPQ);
        if (fast) {
            Dp = gD + (size_t)qid * CANDPQ; Ip = gI + (size_t)qid * CANDPQ;
            m = (int)cnt; sc = 256.f / sqrtf(capq);
        } else {
            // slow path: local re-collect with cap retry (rare / correctness net)
            const float a = z[qid * 6 + 0], b = z[qid * 6 + 1], c = z[qid * 6 + 2];
            const float q2 = fmaf(a, a, fmaf(b, b, c * c));
            float capL = capq;
            unsigned int cc = cnt;
            for (int att = 0; att < 6; ++att) {
                unsigned int base = cc < 8u ? 8u : cc;
                base = base > 8192u ? 8192u : base;   // clamp: stale/poisoned counters can't collapse cap
                capL *= __powf(384.f / (float)base, 0.6666667f);
                if (tid == 0) lcnt = 0u;
                __syncthreads();
                for (int jj = tid; jj < N; jj += KT) {
                    const float4 P = pts[jj];
                    const float dt = fmaf(a, P.x, fmaf(b, P.y, c * P.z));
                    const float d2 = fmaf(-2.f, dt, q2 + P.w);
                    if (d2 < capL) {
                        const unsigned int pos = atomicAdd(&lcnt, 1u);
                        if (pos < (unsigned int)CANDPQ) { candL[pos] = sqrtf(fmaxf(d2, 0.f)); candIL[pos] = jj; }
                    }
                }
                __syncthreads();
                cc = lcnt;
                if (cc >= K && cc <= (unsigned int)CANDPQ) break;
            }
            Dp = candL; Ip = candIL;
            m = (int)(cc <= (unsigned int)CANDPQ ? cc : (unsigned int)CANDPQ);
            sc = 256.f / sqrtf(capL);
        }
        // select k-th via 256-bin hist + tiny lexicographic rank
        fh[tid] = 0u;
        __syncthreads();
        for (int i = tid; i < m; i += KT) {
            int bb = (int)(Dp[i] * sc); bb = bb < 255 ? bb : 255;
            atomicAdd(&fh[bb], 1u);
        }
        __syncthreads();
        scan_find<256>(fh, K, &s_b, &s_tot, wtot, tid);
        const int bsel = s_b < 0 ? 255 : s_b;
        unsigned int vv = (tid < bsel) ? fh[tid] : 0u;
        vv = wredu(vv);
        if (lane == 0) wtot[wid] = vv;
        if (tid == 0) { tcnt = 0u; s_hsel = 3.4e38f; s_isel = 0x7fffffff; }
        __syncthreads();
        const unsigned int Cb = wtot[0] + wtot[1] + wtot[2] + wtot[3];
        for (int i = tid; i < m; i += KT) {
            int bb = (int)(Dp[i] * sc); bb = bb < 255 ? bb : 255;
            if (bb == bsel) {
                const unsigned int p = atomicAdd(&tcnt, 1u);
                if (p < (unsigned int)TINY) { tinyD[p] = Dp[i]; tinyI[p] = Ip[i]; }
            }
        }
        __syncthreads();
        const int c2 = (int)tcnt;
        const int need = (int)K - 1 - (int)Cb;
        if (c2 <= TINY) {
            for (int i = tid; i < c2; i += KT) {
                const float di = tinyD[i]; const int ii = tinyI[i];
                int r = 0;
                for (int j2 = 0; j2 < c2; ++j2) {
                    const float dj = tinyD[j2];
                    if (dj < di || (dj == di && tinyI[j2] < ii)) ++r;
                }
                if (r == need) { s_hsel = di; s_isel = ii; }
            }
        } else {
            for (int i = tid; i < m; i += KT) {
                const float di = Dp[i]; const int ii = Ip[i];
                int r = 0;
                for (int j2 = 0; j2 < m; ++j2) {
                    const float dj = Dp[j2];
                    if (dj < di || (dj == di && Ip[j2] < ii)) ++r;
                }
                if (r == (int)K - 1) { s_hsel = di; s_isel = ii; }
            }
        }
        __syncthreads();
        const float hS = s_hsel; const int iS = s_isel;
        const float hcl = fmaxf(hS, EPS_KNN);
        const float inv2h2 = 1.f / (2.f * hcl * hcl);
        float ws = 0.f, ax = 0.f, ay = 0.f, az = 0.f;
        for (int i = tid; i < m; i += KT) {
            const float s = Dp[i]; const int jj = Ip[i];
            if (s < hS || (s == hS && jj <= iS)) {
                const float w = expf(-(s * s) * inv2h2);
                const float* vp = (jj < N0) ? (v0 + 3 * (size_t)jj) : (v1 + 3 * (size_t)(jj - N0));
                ws += w; ax = fmaf(w, vp[0], ax); ay = fmaf(w, vp[1], ay); az = fmaf(w, vp[2], az);
            }
        }
        ws = wredf(ws); ax = wredf(ax); ay = wredf(ay); az = wredf(az);
        if (lane == 0) { redbuf[wid][0] = ws; redbuf[wid][1] = ax; redbuf[wid][2] = ay; redbuf[wid][3] = az; }
        __syncthreads();
        if (tid == 0) {
            const float wsum = redbuf[0][0] + redbuf[1][0] + redbuf[2][0] + redbuf[3][0];
            const float axs  = redbuf[0][1] + redbuf[1][1] + redbuf[2][1] + redbuf[3][1];
            const float ays  = redbuf[0][2] + redbuf[1][2] + redbuf[2][2] + redbuf[3][2];
            const float azs  = redbuf[0][3] + redbuf[1][3] + redbuf[2][3] + redbuf[3][3];
            const float inv = 1.f / (wsum + EPS_KNN);
            const float ux = axs * inv, uy = ays * inv, uz = azs * inv;
            const float d0 = xdot[qid * 3 + 0], d1 = xdot[qid * 3 + 1], d2v = xdot[qid * 3 + 2];
            const float nu = fmaxf(sqrtf(ux * ux + uy * uy + uz * uz), EPS_COS);
            const float nd = fmaxf(sqrtf(d0 * d0 + d1 * d1 + d2v * d2v), EPS_COS);
            const float cs = 1.f - (ux * d0 + uy * d1 + uz * d2v) / (nu * nd);
            const float ex = ux - d0, ey = uy - d1, ez = uz - d2v;
            const float l2 = ex * ex + ey * ey + ez * ez;
            out[qid * 6 + 0] = d0; out[qid * 6 + 1] = d1; out[qid * 6 + 2] = d2v;
            out[qid * 6 + 3] = cs; out[qid * 6 + 4] = cs; out[qid * 6 + 5] = l2;
        }
        __syncthreads();
    }
}

// ---------------- fallback: round-3 monolithic knn (proven, used if ws too small) ----
__global__ __launch_bounds__(KT) void knn_fallback(
    const float* __restrict__ z,
    const float* __restrict__ x0, const float* __restrict__ x1,
    const float* __restrict__ v0, const float* __restrict__ v1,
    const float* __restrict__ xdot, const int* __restrict__ kp,
    float* __restrict__ out, int B, int N0, int N1)
{
    const int N = N0 + N1;
    const unsigned int K = (unsigned int)kp[0];
    __shared__ unsigned int hist[QB][NBUCKET];
    float (*candD)[CANDMAX] = (float (*)[CANDMAX])&hist[0][0];
    int   (*candI)[CANDMAX] = (int (*)[CANDMAX])((char*)&hist[0][0] + sizeof(float) * QB * CANDMAX);
    __shared__ unsigned int fh[256];
    __shared__ float tinyD[TINY];
    __shared__ int   tinyI[TINY];
    __shared__ unsigned int tcnt;
    __shared__ unsigned int candCnt[QB];
    __shared__ float capv[QB];
    __shared__ float hselv[QB];
    __shared__ int   iselv[QB];
    __shared__ int   doneQ[QB];
    __shared__ int   anyleft;
    __shared__ unsigned int wtot[4];
    __shared__ int s_b;
    __shared__ unsigned int s_tot;
    __shared__ float qsh[QB][4];
    __shared__ float redbuf[4][QB * 4];
    const int tid = threadIdx.x, lane = tid & 63, wid = tid >> 6;
    const int qbase = blockIdx.x * QB;

    if (tid < QB) {
        const int qid = qbase + tid;
        float a = 0.f, b = 0.f, c = 0.f;
        if (qid < B) { a = z[qid * 6 + 0]; b = z[qid * 6 + 1]; c = z[qid * 6 + 2]; }
        qsh[tid][0] = a; qsh[tid][1] = b; qsh[tid][2] = c;
        qsh[tid][3] = fmaf(a, a, fmaf(b, b, c * c));
    }
    for (int i = tid; i < QB * NBUCKET; i += KT) (&hist[0][0])[i] = 0u;
    __syncthreads();
    float qx[QB], qy[QB], qz[QB], q2[QB];
#pragma unroll
    for (int q = 0; q < QB; ++q) { qx[q] = qsh[q][0]; qy[q] = qsh[q][1]; qz[q] = qsh[q][2]; q2[q] = qsh[q][3]; }

    auto doPoint = [&](float px, float py, float pz, int idx, auto&& fn) {
        const float p2 = fmaf(px, px, fmaf(py, py, pz * pz));
#pragma unroll
        for (int q = 0; q < QB; ++q) {
            const float dt = fmaf(qx[q], px, fmaf(qy[q], py, qz[q] * pz));
            const float d2 = fmaf(-2.f, dt, q2[q] + p2);
            fn(q, idx, d2);
        }
    };
    auto sweepAll = [&](auto&& fn) {
        const int G0 = N0 >> 2;
        for (int g = tid; g < G0; g += KT) {
            const float4* bp = (const float4*)(x0 + 12 * (size_t)g);
            const float4 A = bp[0], Bv = bp[1], C = bp[2];
            doPoint(A.x, A.y, A.z, 4 * g + 0, fn);
            doPoint(A.w, Bv.x, Bv.y, 4 * g + 1, fn);
            doPoint(Bv.z, Bv.w, C.x, 4 * g + 2, fn);
            doPoint(C.y, C.z, C.w, 4 * g + 3, fn);
        }
        for (int j = (G0 << 2) + tid; j < N0; j += KT)
            doPoint(x0[3 * j], x0[3 * j + 1], x0[3 * j + 2], j, fn);
        const int G1 = N1 >> 2;
        for (int g = tid; g < G1; g += KT) {
            const float4* bp = (const float4*)(x1 + 12 * (size_t)g);
            const float4 A = bp[0], Bv = bp[1], C = bp[2];
            doPoint(A.x, A.y, A.z, N0 + 4 * g + 0, fn);
            doPoint(A.w, Bv.x, Bv.y, N0 + 4 * g + 1, fn);
            doPoint(Bv.z, Bv.w, C.x, N0 + 4 * g + 2, fn);
            doPoint(C.y, C.z, C.w, N0 + 4 * g + 3, fn);
        }
        for (int j = (G1 << 2) + tid; j < N1; j += KT)
            doPoint(x1[3 * j], x1[3 * j + 1], x1[3 * j + 2], N0 + j, fn);
    };

    for (int s = tid; s < 2048; s += KT) {
        const int j = (int)(((long long)s * (long long)N) >> 11);
        float px, py, pz;
        if (j < N0) { px = x0[3 * j]; py = x0[3 * j + 1]; pz = x0[3 * j + 2]; }
        else { const int j2 = j - N0; px = x1[3 * j2]; py = x1[3 * j2 + 1]; pz = x1[3 * j2 + 2]; }
        const float p2 = fmaf(px, px, fmaf(py, py, pz * pz));
#pragma unroll
        for (int q = 0; q < QB; ++q) {
            const float dt = fmaf(qx[q], px, fmaf(qy[q], py, qz[q] * pz));
            float d2 = fmaf(-2.f, dt, q2[q] + p2);
            d2 = fmaxf(d2, 0.f);
            int bu = (int)(__float_as_uint(d2) >> 20);
            bu = bu < (NBUCKET - 1) ? bu : (NBUCKET - 1);
            atomicAdd(&hist[q][bu], 1u);
        }
    }
    __syncthreads();
    for (int q = 0; q < QB; ++q) {
        scan_find<NBUCKET>(&hist[q][0], TSAMP, &s_b, &s_tot, wtot, tid);
        if (tid == 0) {
            int b = s_b; if (b < 0) b = NBUCKET - 1;
            const unsigned int ub = (unsigned int)(b + 1);
            const float cap = (ub >= 2040u) ? 3.4e38f : __uint_as_float(ub << 20);
            capv[q] = (qbase + q < B) ? cap : -1.f;
            doneQ[q] = (qbase + q < B) ? 0 : 1;
        }
        __syncthreads();
    }
    for (int attempt = 0; attempt < 4; ++attempt) {
        if (tid == 0) anyleft = 0;
        if (tid < QB && !doneQ[tid]) candCnt[tid] = 0u;
        __syncthreads();
        float rcap[QB];
#pragma unroll
        for (int q = 0; q < QB; ++q) rcap[q] = doneQ[q] ? -1.f : capv[q];
        sweepAll([&](int q, int j, float d2) {
            if (d2 < rcap[q]) {
                const unsigned int pos = atomicAdd(&candCnt[q], 1u);
                if (pos < (unsigned int)CANDMAX) { candD[q][pos] = sqrtf(fmaxf(d2, 0.f)); candI[q][pos] = j; }
            }
        });
        __syncthreads();
        if (tid < QB && !doneQ[tid]) {
            const unsigned int c = candCnt[tid];
            if (c >= K && c <= (unsigned int)CANDMAX) doneQ[tid] = 1;
            else {
                const unsigned int cc = c < 8u ? 8u : c;
                capv[tid] *= __powf(384.f / (float)cc, 0.6666667f);
                anyleft = 1;
            }
        }
        __syncthreads();
        if (!anyleft) break;
    }
    for (int q = 0; q < QB; ++q) {
        if (qbase + q >= B) continue;
        const unsigned int cnt = candCnt[q];
        const int m = (int)(cnt < (unsigned int)CANDMAX ? cnt : (unsigned int)CANDMAX);
        fh[tid] = 0u;
        __syncthreads();
        const float sc = 256.f / sqrtf(capv[q]);
        for (int i = tid; i < m; i += KT) {
            int b = (int)(candD[q][i] * sc); b = b < 255 ? b : 255;
            atomicAdd(&fh[b], 1u);
        }
        __syncthreads();
        scan_find<256>(fh, K, &s_b, &s_tot, wtot, tid);
        const int bsel = s_b < 0 ? 255 : s_b;
        unsigned int v = (tid < bsel) ? fh[tid] : 0u;
        v = wredu(v);
        if (lane == 0) wtot[wid] = v;
        if (tid == 0) tcnt = 0u;
        __syncthreads();
        const unsigned int Cb = wtot[0] + wtot[1] + wtot[2] + wtot[3];
        for (int i = tid; i < m; i += KT) {
            int b = (int)(candD[q][i] * sc); b = b < 255 ? b : 255;
            if (b == bsel) {
                const unsigned int p = atomicAdd(&tcnt, 1u);
                if (p < (unsigned int)TINY) { tinyD[p] = candD[q][i]; tinyI[p] = candI[q][i]; }
            }
        }
        __syncthreads();
        const int c2 = (int)tcnt;
        const int need = (int)K - 1 - (int)Cb;
        if (c2 <= TINY) {
            for (int i = tid; i < c2; i += KT) {
                const float di = tinyD[i]; const int ii = tinyI[i];
                int r = 0;
                for (int j2 = 0; j2 < c2; ++j2) {
                    const float dj = tinyD[j2];
                    if (dj < di || (dj == di && tinyI[j2] < ii)) ++r;
                }
                if (r == need) { hselv[q] = di; iselv[q] = ii; }
            }
        } else {
            for (int i = tid; i < m; i += KT) {
                const float di = candD[q][i]; const int ii = candI[q][i];
                int r = 0;
                for (int j2 = 0; j2 < m; ++j2) {
                    const float dj = candD[q][j2];
                    if (dj < di || (dj == di && candI[q][j2] < ii)) ++r;
                }
                if (r == (int)K - 1) { hselv[q] = di; iselv[q] = ii; }
            }
        }
        __syncthreads();
    }
    for (int q = 0; q < QB; ++q) {
        if (qbase + q >= B) continue;
        const float hS = hselv[q];
        const int iS = iselv[q];
        const float hcl = fmaxf(hS, EPS_KNN);
        const float inv2h2 = 1.f / (2.f * hcl * hcl);
        const unsigned int cnt = candCnt[q];
        const int m = (int)(cnt < (unsigned int)CANDMAX ? cnt : (unsigned int)CANDMAX);
        float ws = 0.f, ax = 0.f, ay = 0.f, az = 0.f;
        for (int i = tid; i < m; i += KT) {
            const float s = candD[q][i];
            const int j = candI[q][i];
            if (s < hS || (s == hS && j <= iS)) {
                const float w = expf(-(s * s) * inv2h2);
                const float* vp = (j < N0) ? (v0 + 3 * (size_t)j) : (v1 + 3 * (size_t)(j - N0));
                ws += w; ax = fmaf(w, vp[0], ax); ay = fmaf(w, vp[1], ay); az = fmaf(w, vp[2], az);
            }
        }
        ws = wredf(ws); ax = wredf(ax); ay = wredf(ay); az = wredf(az);
        if (lane == 0) {
            redbuf[wid][q * 4 + 0] = ws; redbuf[wid][q * 4 + 1] = ax;
            redbuf[wid][q * 4 + 2] = ay; redbuf[wid][q * 4 + 3] = az;
        }
    }
    __syncthreads();
    if (tid < QB) {
        const int q = tid, qid = qbase + q;
        if (qid < B) {
            const float ws = redbuf[0][q*4+0] + redbuf[1][q*4+0] + redbuf[2][q*4+0] + redbuf[3][q*4+0];
            const float ax = redbuf[0][q*4+1] + redbuf[1][q*4+1] + redbuf[2][q*4+1] + redbuf[3][q*4+1];
            const float ay = redbuf[0][q*4+2] + redbuf[1][q*4+2] + redbuf[2][q*4+2] + redbuf[3][q*4+2];
            const float az = redbuf[0][q*4+3] + redbuf[1][q*4+3] + redbuf[2][q*4+3] + redbuf[3][q*4+3];
            const float inv = 1.f / (ws + EPS_KNN);
            const float ux = ax * inv, uy = ay * inv, uz = az * inv;
            const float d0 = xdot[qid * 3 + 0], d1 = xdot[qid * 3 + 1], d2v = xdot[qid * 3 + 2];
            const float nu = fmaxf(sqrtf(ux * ux + uy * uy + uz * uz), EPS_COS);
            const float nd = fmaxf(sqrtf(d0 * d0 + d1 * d1 + d2v * d2v), EPS_COS);
            const float cs = 1.f - (ux * d0 + uy * d1 + uz * d2v) / (nu * nd);
            const float ex = ux - d0, ey = uy - d1, ez = uz - d2v;
            const float l2 = ex * ex + ey * ey + ez * ez;
            out[qid * 6 + 0] = d0; out[qid * 6 + 1] = d1; out[qid * 6 + 2] = d2v;
            out[qid * 6 + 3] = cs; out[qid * 6 + 4] = cs; out[qid * 6 + 5] = l2;
        }
    }
}

extern "C" void kernel_launch(void* const* d_in, const int* in_sizes, int n_in,
                              void* d_out, int out_size, void* d_ws, size_t ws_size,
                              hipStream_t stream)
{
    const float* z  = (const float*)d_in[0];
    const float* tp = (const float*)d_in[1];
    const float* x0 = (const float*)d_in[2];
    const float* x1 = (const float*)d_in[3];
    const float* v0 = (const float*)d_in[4];
    const float* v1 = (const float*)d_in[5];
    const float* W1 = (const float*)d_in[6];
    const float* b1 = (const float*)d_in[7];
    const float* W2 = (const float*)d_in[8];
    const float* b2 = (const float*)d_in[9];
    const float* W3 = (const float*)d_in[10];
    const float* b3 = (const float*)d_in[11];
    const int*   kp = (const int*)d_in[12];
    float* outp = (float*)d_out;
    const int B  = in_sizes[0] / 6;
    const int N0 = in_sizes[2] / 3;
    const int N1 = in_sizes[3] / 3;
    const int N  = N0 + N1;

    // ws layout
    size_t off = 0;
    auto alloc = [&](size_t bytes) { size_t o = off; off = (off + bytes + 255) & ~(size_t)255; return o; };
    const size_t o_xdot = alloc((size_t)B * 3 * sizeof(float));
    const size_t o_pts  = alloc((size_t)N * sizeof(float4));
    const size_t o_cap  = alloc((size_t)B * sizeof(float));
    const size_t o_cnt  = alloc((size_t)B * sizeof(unsigned int));
    const size_t o_gD   = alloc((size_t)B * CANDPQ * sizeof(float));
    const size_t o_gI   = alloc((size_t)B * CANDPQ * sizeof(int));
    const bool split = ws_size >= off;

    float* xdot = (float*)((char*)d_ws + o_xdot);

    hipLaunchKernelGGL(mlp_kernel, dim3((B + MQ - 1) / MQ), dim3(512), 0, stream,
                       z, tp, W1, b1, W2, b2, W3, b3, xdot, B);
    if (split) {
        float4* pts = (float4*)((char*)d_ws + o_pts);
        float* capg = (float*)((char*)d_ws + o_cap);
        unsigned int* gcnt = (unsigned int*)((char*)d_ws + o_cnt);
        float* gD = (float*)((char*)d_ws + o_gD);
        int*   gI = (int*)((char*)d_ws + o_gI);
        const int QG = (B + QA - 1) / QA;
        hipLaunchKernelGGL(pack_kernel, dim3((N + 255) / 256), dim3(256), 0, stream,
                           x0, x1, pts, N0, N);
        hipLaunchKernelGGL(sample_kernel, dim3(B), dim3(KT), 0, stream,
                           z, pts, capg, gcnt, B, N);
        hipLaunchKernelGGL(sweepA_kernel, dim3(QG * SLICES), dim3(KT), 0, stream,
                           z, pts, capg, gcnt, gD, gI, B, N);
        hipLaunchKernelGGL(finalB_kernel, dim3((B + QBF - 1) / QBF), dim3(KT), 0, stream,
                           z, pts, v0, v1, xdot, kp, capg, gcnt, gD, gI, outp, B, N0, N1);
    } else {
        hipLaunchKernelGGL(knn_fallback, dim3((B + QB - 1) / QB), dim3(KT), 0, stream,
                           z, x0, x1, v0, v1, xdot, kp, outp, B, N0, N1);
    }
}

// Round 8
// 286.532 us; speedup vs baseline: 1.6760x; 1.3200x over previous
//
#include <hip/hip_runtime.h>
#include <math.h>

#define KT 256
#define QA 8          // queries per sweepA block
#define SLICES 4      // point slices
#define LCAP 512      // LDS candidate capacity per query per block (sweepA)
#define QBF 2         // queries per finalB block
#define CANDMAXF 2048 // finalB LDS candidate capacity (>= runtime candpq)
#define NBUCKET 2048
#define TINY 256
#define EPS_KNN 1e-12f
#define EPS_COS 1e-8f
#define MQ 8
// fallback (round-3) params
#define QB 2
#define CANDMAX 1024
#define TSAMP_FB 8u

__device__ __forceinline__ float wredf(float v) {
#pragma unroll
    for (int off = 32; off > 0; off >>= 1) v += __shfl_xor(v, off, 64);
    return v;
}
__device__ __forceinline__ unsigned int wredu(unsigned int v) {
#pragma unroll
    for (int off = 32; off > 0; off >>= 1) v += (unsigned int)__shfl_xor((int)v, off, 64);
    return v;
}

// Block-cooperative: smallest bucket b with cum(h[0..b]) >= T. Ends with sync.
template<int NB>
__device__ void scan_find(const unsigned int* h, unsigned int T,
                          int* out_b, unsigned int* out_total,
                          unsigned int* wtot, int tid)
{
    constexpr int CH = NB / KT;
    const int lane = tid & 63, wid = tid >> 6;
    const int base = tid * CH;
    unsigned int s = 0;
#pragma unroll
    for (int u = 0; u < CH; ++u) s += h[base + u];
    unsigned int incl = s;
#pragma unroll
    for (int d = 1; d < 64; d <<= 1) {
        unsigned int n = (unsigned int)__shfl_up((int)incl, d, 64);
        if (lane >= d) incl += n;
    }
    if (tid == 0) *out_b = -1;
    if (lane == 63) wtot[wid] = incl;
    __syncthreads();
    unsigned int offs = 0;
    for (int w = 0; w < wid; ++w) offs += wtot[w];
    const unsigned int total = wtot[0] + wtot[1] + wtot[2] + wtot[3];
    const unsigned int excl = offs + (incl - s);
    if (excl < T && T <= excl + s) {
        unsigned int c = excl;
        for (int u = 0; u < CH; ++u) {
            c += h[base + u];
            if (c >= T) { *out_b = base + u; break; }
        }
    }
    if (tid == 0) *out_total = total;
    __syncthreads();
}

// ---------------- pack: {x,y,z,|p|^2} ----------------
__global__ __launch_bounds__(256) void pack_kernel(
    const float* __restrict__ x0, const float* __restrict__ x1,
    float4* __restrict__ pts, int N0, int N)
{
    const int i = blockIdx.x * 256 + threadIdx.x;
    if (i >= N) return;
    float px, py, pz;
    if (i < N0) { px = x0[3 * i]; py = x0[3 * i + 1]; pz = x0[3 * i + 2]; }
    else { const int j = i - N0; px = x1[3 * j]; py = x1[3 * j + 1]; pz = x1[3 * j + 2]; }
    const float p2 = fmaf(px, px, fmaf(py, py, pz * pz));
    pts[i] = make_float4(px, py, pz, p2);
}

// ---------------- MLP (proven) ----------------
__global__ __launch_bounds__(512) void mlp_kernel(
    const float* __restrict__ z, const float* __restrict__ tp,
    const float* __restrict__ W1, const float* __restrict__ b1,
    const float* __restrict__ W2, const float* __restrict__ b2,
    const float* __restrict__ W3, const float* __restrict__ b3,
    float* __restrict__ xdot, int B)
{
    __shared__ float h1[MQ][512];
    __shared__ float red[8][MQ * 3];
    const int tid = threadIdx.x, lane = tid & 63, wid = tid >> 6;
    const int qbase = blockIdx.x * MQ;
    const float t = tp[0];

    for (int idx = tid; idx < MQ * 512; idx += 512) {
        const int q = idx >> 9, j = idx & 511;
        const int qid = qbase + q;
        float v = 0.f;
        if (qid < B) {
            const float a = z[qid * 6 + 0], b = z[qid * 6 + 1], c = z[qid * 6 + 2];
            v = fmaf(a, W1[j], fmaf(b, W1[512 + j], fmaf(c, W1[1024 + j], fmaf(t, W1[1536 + j], b1[j]))));
            v = fmaxf(v, 0.f);
        }
        h1[q][j] = v;
    }
    __syncthreads();

    const int col = wid * 64 + lane;
    float acc[MQ];
#pragma unroll
    for (int q = 0; q < MQ; ++q) acc[q] = b2[col];

    float w[4], wn[4];
#pragma unroll
    for (int u = 0; u < 4; ++u) w[u] = W2[u * 512 + col];
    for (int r = 0; r < 512; r += 4) {
        const int rn = r + 4;
        if (rn < 512) {
#pragma unroll
            for (int u = 0; u < 4; ++u) wn[u] = W2[(rn + u) * 512 + col];
        }
        float4 hv[MQ];
#pragma unroll
        for (int q = 0; q < MQ; ++q) hv[q] = *(const float4*)&h1[q][r];
#pragma unroll
        for (int q = 0; q < MQ; ++q) {
            acc[q] = fmaf(hv[q].x, w[0], acc[q]);
            acc[q] = fmaf(hv[q].y, w[1], acc[q]);
            acc[q] = fmaf(hv[q].z, w[2], acc[q]);
            acc[q] = fmaf(hv[q].w, w[3], acc[q]);
        }
#pragma unroll
        for (int u = 0; u < 4; ++u) w[u] = wn[u];
    }

    const float wc0 = W3[col * 3 + 0], wc1 = W3[col * 3 + 1], wc2 = W3[col * 3 + 2];
#pragma unroll
    for (int q = 0; q < MQ; ++q) {
        const float h = fmaxf(acc[q], 0.f);
        float p0 = h * wc0, p1 = h * wc1, p2 = h * wc2;
        p0 = wredf(p0); p1 = wredf(p1); p2 = wredf(p2);
        if (lane == 0) { red[wid][q * 3 + 0] = p0; red[wid][q * 3 + 1] = p1; red[wid][q * 3 + 2] = p2; }
    }
    __syncthreads();
    if (tid < MQ * 3) {
        const int q = tid / 3, d = tid % 3;
        float s = 0.f;
#pragma unroll
        for (int w8 = 0; w8 < 8; ++w8) s += red[w8][q * 3 + d];
        const int qid = qbase + q;
        if (qid < B) xdot[qid * 3 + d] = s + b3[d];
    }
}

// ---------------- sample: 1 query/block, cap + zero counter ----------------
__global__ __launch_bounds__(KT) void sample_kernel(
    const float* __restrict__ z, const float4* __restrict__ pts,
    float* __restrict__ capg, unsigned int* __restrict__ gcnt,
    int B, int N, unsigned int ts)
{
    __shared__ unsigned int hist[NBUCKET];
    __shared__ unsigned int wtot[4];
    __shared__ int s_b; __shared__ unsigned int s_tot;
    const int tid = threadIdx.x, qid = blockIdx.x;
    if (qid >= B) return;
    for (int i = tid; i < NBUCKET; i += KT) hist[i] = 0u;
    __syncthreads();
    const float a = z[qid * 6 + 0], b = z[qid * 6 + 1], c = z[qid * 6 + 2];
    const float q2 = fmaf(a, a, fmaf(b, b, c * c));
    for (int s = tid; s < 2048; s += KT) {
        const int j = (int)(((long long)s * (long long)N) >> 11);
        const float4 P = pts[j];
        const float dt = fmaf(a, P.x, fmaf(b, P.y, c * P.z));
        float d2 = fmaf(-2.f, dt, q2 + P.w);
        d2 = fmaxf(d2, 0.f);
        int bu = (int)(__float_as_uint(d2) >> 20);
        bu = bu < (NBUCKET - 1) ? bu : (NBUCKET - 1);
        atomicAdd(&hist[bu], 1u);
    }
    __syncthreads();
    scan_find<NBUCKET>(hist, ts, &s_b, &s_tot, wtot, tid);
    if (tid == 0) {
        int bb = s_b; if (bb < 0) bb = NBUCKET - 1;
        const unsigned int ub = (unsigned int)(bb + 1);
        capg[qid] = (ub >= 2040u) ? 3.4e38f : __uint_as_float(ub << 20);
        gcnt[qid] = 0u;
    }
}

// ---------------- sweepA: LDS-staged candidate collection ----------------
__global__ __launch_bounds__(KT) void sweepA_kernel(
    const float* __restrict__ z, const float4* __restrict__ pts,
    const float* __restrict__ capg, unsigned int* __restrict__ gcnt,
    float* __restrict__ gD, int* __restrict__ gI, int B, int N, int candpq)
{
    __shared__ float ldsD[QA][LCAP];
    __shared__ int   ldsI[QA][LCAP];
    __shared__ unsigned int lcnt[QA];
    __shared__ unsigned int gbase[QA];
    const int tid = threadIdx.x;
    const int slice = blockIdx.x & (SLICES - 1);
    const int qg = blockIdx.x / SLICES;
    const int q0 = qg * QA;
    if (tid < QA) lcnt[tid] = 0u;
    float qx[QA], qy[QA], qz[QA], qw[QA], cp[QA];
#pragma unroll
    for (int u = 0; u < QA; ++u) {
        const int qid = q0 + u;
        float a = 0.f, b = 0.f, c = 0.f, cap = -1.f;
        if (qid < B) { a = z[qid * 6 + 0]; b = z[qid * 6 + 1]; c = z[qid * 6 + 2]; cap = capg[qid]; }
        qx[u] = a; qy[u] = b; qz[u] = c; qw[u] = fmaf(a, a, fmaf(b, b, c * c)); cp[u] = cap;
    }
    __syncthreads();
    const int slen = (N + SLICES - 1) / SLICES;
    const int s0 = slice * slen;
    const int s1 = min(N, s0 + slen);
    int j = s0 + tid;
    bool valid = j < s1;
    float4 P;
    if (valid) P = pts[j];
    while (valid) {
        const int jn = j + KT;
        const bool vn = jn < s1;
        float4 Pn;
        if (vn) Pn = pts[jn];
#pragma unroll
        for (int u = 0; u < QA; ++u) {
            const float dt = fmaf(qx[u], P.x, fmaf(qy[u], P.y, qz[u] * P.z));
            const float d2 = fmaf(-2.f, dt, qw[u] + P.w);
            if (d2 < cp[u]) {
                const unsigned int pos = atomicAdd(&lcnt[u], 1u);
                if (pos < (unsigned int)LCAP) {
                    ldsD[u][pos] = sqrtf(fmaxf(d2, 0.f));
                    ldsI[u][pos] = j;
                }
            }
        }
        j = jn; valid = vn; P = Pn;
    }
    __syncthreads();
    if (tid < QA) {
        const unsigned int c = lcnt[tid];
        const unsigned int clip = c < (unsigned int)LCAP ? c : (unsigned int)LCAP;
        const unsigned int add = clip + (c > (unsigned int)LCAP ? 1000000u : 0u);
        gbase[tid] = (q0 + tid < B) ? atomicAdd(&gcnt[q0 + tid], add) : 0u;
        lcnt[tid] = clip;
    }
    __syncthreads();
    for (int u = 0; u < QA; ++u) {
        const int qid = q0 + u;
        if (qid >= B) continue;
        const unsigned int clip = lcnt[u];
        const unsigned int base = gbase[u];
        for (unsigned int i = tid; i < clip; i += KT) {
            const unsigned int off = base + i;
            if (off < (unsigned int)candpq) {
                gD[(size_t)qid * candpq + off] = ldsD[u][i];
                gI[(size_t)qid * candpq + off] = ldsI[u][i];
            }
        }
    }
}

// ---------------- finalB: exact k-th + weighted accumulation + metrics ----------------
__global__ __launch_bounds__(KT) void finalB_kernel(
    const float* __restrict__ z, const float4* __restrict__ pts,
    const float* __restrict__ v0, const float* __restrict__ v1,
    const float* __restrict__ xdot, const int* __restrict__ kp,
    const float* __restrict__ capg, const unsigned int* __restrict__ gcnt,
    const float* __restrict__ gD, const int* __restrict__ gI,
    float* __restrict__ out, int B, int N0, int N1, int candpq)
{
    const int N = N0 + N1;
    const unsigned int K = (unsigned int)kp[0];
    __shared__ float candL[CANDMAXF];
    __shared__ int   candIL[CANDMAXF];
    __shared__ unsigned int fh[256];
    __shared__ float tinyD[TINY];
    __shared__ int   tinyI[TINY];
    __shared__ unsigned int tcnt, lcnt;
    __shared__ unsigned int wtot[4];
    __shared__ int s_b; __shared__ unsigned int s_tot;
    __shared__ float redbuf[4][4];
    __shared__ float s_hsel; __shared__ int s_isel;
    const int tid = threadIdx.x, lane = tid & 63, wid = tid >> 6;

    for (int u = 0; u < QBF; ++u) {
        const int qid = blockIdx.x * QBF + u;
        if (qid >= B) continue;                    // uniform across block
        const unsigned int cnt = gcnt[qid];
        const float capq = capg[qid];
        int m; float sc;
        const bool fast = (cnt >= K && cnt <= (unsigned int)candpq);
        if (fast) {
            // stage candidate list into LDS (coalesced), all later passes hit LDS
            m = (int)cnt; sc = 256.f / sqrtf(capq);
            const float* gDq = gD + (size_t)qid * candpq;
            const int*   gIq = gI + (size_t)qid * candpq;
            for (int i = tid; i < m; i += KT) { candL[i] = gDq[i]; candIL[i] = gIq[i]; }
            __syncthreads();
        } else {
            // slow path: local re-collect with cap retry (rare correctness net),
            // batch-4 pipelined loads
            const float a = z[qid * 6 + 0], b = z[qid * 6 + 1], c = z[qid * 6 + 2];
            const float q2 = fmaf(a, a, fmaf(b, b, c * c));
            float capL = capq;
            unsigned int cc = cnt;
            for (int att = 0; att < 5; ++att) {
                unsigned int base = cc < 8u ? 8u : cc;
                base = base > 8192u ? 8192u : base;   // clamp: stale counters can't collapse cap
                capL *= __powf(384.f / (float)base, 0.6666667f);
                if (tid == 0) lcnt = 0u;
                __syncthreads();
                for (int bj = 0; bj < N; bj += 4 * KT) {
                    float4 P[4]; int idx[4]; bool val[4];
#pragma unroll
                    for (int w4 = 0; w4 < 4; ++w4) {
                        idx[w4] = bj + w4 * KT + tid;
                        val[w4] = idx[w4] < N;
                        if (val[w4]) P[w4] = pts[idx[w4]];
                    }
#pragma unroll
                    for (int w4 = 0; w4 < 4; ++w4) {
                        if (val[w4]) {
                            const float dt = fmaf(a, P[w4].x, fmaf(b, P[w4].y, c * P[w4].z));
                            const float d2 = fmaf(-2.f, dt, q2 + P[w4].w);
                            if (d2 < capL) {
                                const unsigned int pos = atomicAdd(&lcnt, 1u);
                                if (pos < (unsigned int)CANDMAXF) { candL[pos] = sqrtf(fmaxf(d2, 0.f)); candIL[pos] = idx[w4]; }
                            }
                        }
                    }
                }
                __syncthreads();
                cc = lcnt;
                if (cc >= K && cc <= (unsigned int)CANDMAXF) break;
            }
            m = (int)(cc <= (unsigned int)CANDMAXF ? cc : (unsigned int)CANDMAXF);
            sc = 256.f / sqrtf(capL);
        }
        // select k-th via 256-bin hist + tiny lexicographic rank (LDS-resident)
        fh[tid] = 0u;
        __syncthreads();
        for (int i = tid; i < m; i += KT) {
            int bb = (int)(candL[i] * sc); bb = bb < 255 ? bb : 255;
            atomicAdd(&fh[bb], 1u);
        }
        __syncthreads();
        scan_find<256>(fh, K, &s_b, &s_tot, wtot, tid);
        const int bsel = s_b < 0 ? 255 : s_b;
        unsigned int vv = (tid < bsel) ? fh[tid] : 0u;
        vv = wredu(vv);
        if (lane == 0) wtot[wid] = vv;
        if (tid == 0) { tcnt = 0u; s_hsel = 3.4e38f; s_isel = 0x7fffffff; }
        __syncthreads();
        const unsigned int Cb = wtot[0] + wtot[1] + wtot[2] + wtot[3];
        for (int i = tid; i < m; i += KT) {
            int bb = (int)(candL[i] * sc); bb = bb < 255 ? bb : 255;
            if (bb == bsel) {
                const unsigned int p = atomicAdd(&tcnt, 1u);
                if (p < (unsigned int)TINY) { tinyD[p] = candL[i]; tinyI[p] = candIL[i]; }
            }
        }
        __syncthreads();
        const int c2 = (int)tcnt;
        const int need = (int)K - 1 - (int)Cb;
        if (c2 <= TINY) {
            for (int i = tid; i < c2; i += KT) {
                const float di = tinyD[i]; const int ii = tinyI[i];
                int r = 0;
                for (int j2 = 0; j2 < c2; ++j2) {
                    const float dj = tinyD[j2];
                    if (dj < di || (dj == di && tinyI[j2] < ii)) ++r;
                }
                if (r == need) { s_hsel = di; s_isel = ii; }
            }
        } else {
            for (int i = tid; i < m; i += KT) {
                const float di = candL[i]; const int ii = candIL[i];
                int r = 0;
                for (int j2 = 0; j2 < m; ++j2) {
                    const float dj = candL[j2];
                    if (dj < di || (dj == di && candIL[j2] < ii)) ++r;
                }
                if (r == (int)K - 1) { s_hsel = di; s_isel = ii; }
            }
        }
        __syncthreads();
        const float hS = s_hsel; const int iS = s_isel;
        const float hcl = fmaxf(hS, EPS_KNN);
        const float inv2h2 = 1.f / (2.f * hcl * hcl);
        float ws = 0.f, ax = 0.f, ay = 0.f, az = 0.f;
        for (int i = tid; i < m; i += KT) {
            const float s = candL[i]; const int jj = candIL[i];
            if (s < hS || (s == hS && jj <= iS)) {
                const float w = expf(-(s * s) * inv2h2);
                const float* vp = (jj < N0) ? (v0 + 3 * (size_t)jj) : (v1 + 3 * (size_t)(jj - N0));
                ws += w; ax = fmaf(w, vp[0], ax); ay = fmaf(w, vp[1], ay); az = fmaf(w, vp[2], az);
            }
        }
        ws = wredf(ws); ax = wredf(ax); ay = wredf(ay); az = wredf(az);
        if (lane == 0) { redbuf[wid][0] = ws; redbuf[wid][1] = ax; redbuf[wid][2] = ay; redbuf[wid][3] = az; }
        __syncthreads();
        if (tid == 0) {
            const float wsum = redbuf[0][0] + redbuf[1][0] + redbuf[2][0] + redbuf[3][0];
            const float axs  = redbuf[0][1] + redbuf[1][1] + redbuf[2][1] + redbuf[3][1];
            const float ays  = redbuf[0][2] + redbuf[1][2] + redbuf[2][2] + redbuf[3][2];
            const float azs  = redbuf[0][3] + redbuf[1][3] + redbuf[2][3] + redbuf[3][3];
            const float inv = 1.f / (wsum + EPS_KNN);
            const float ux = axs * inv, uy = ays * inv, uz = azs * inv;
            const float d0 = xdot[qid * 3 + 0], d1 = xdot[qid * 3 + 1], d2v = xdot[qid * 3 + 2];
            const float nu = fmaxf(sqrtf(ux * ux + uy * uy + uz * uz), EPS_COS);
            const float nd = fmaxf(sqrtf(d0 * d0 + d1 * d1 + d2v * d2v), EPS_COS);
            const float cs = 1.f - (ux * d0 + uy * d1 + uz * d2v) / (nu * nd);
            const float ex = ux - d0, ey = uy - d1, ez = uz - d2v;
            const float l2 = ex * ex + ey * ey + ez * ez;
            out[qid * 6 + 0] = d0; out[qid * 6 + 1] = d1; out[qid * 6 + 2] = d2v;
            out[qid * 6 + 3] = cs; out[qid * 6 + 4] = cs; out[qid * 6 + 5] = l2;
        }
        __syncthreads();
    }
}

// ---------------- fallback: round-3 monolithic knn (proven, used if ws too small) ----
__global__ __launch_bounds__(KT) void knn_fallback(
    const float* __restrict__ z,
    const float* __restrict__ x0, const float* __restrict__ x1,
    const float* __restrict__ v0, const float* __restrict__ v1,
    const float* __restrict__ xdot, const int* __restrict__ kp,
    float* __restrict__ out, int B, int N0, int N1)
{
    const int N = N0 + N1;
    const unsigned int K = (unsigned int)kp[0];
    __shared__ unsigned int hist[QB][NBUCKET];
    float (*candD)[CANDMAX] = (float (*)[CANDMAX])&hist[0][0];
    int   (*candI)[CANDMAX] = (int (*)[CANDMAX])((char*)&hist[0][0] + sizeof(float) * QB * CANDMAX);
    __shared__ unsigned int fh[256];
    __shared__ float tinyD[TINY];
    __shared__ int   tinyI[TINY];
    __shared__ unsigned int tcnt;
    __shared__ unsigned int candCnt[QB];
    __shared__ float capv[QB];
    __shared__ float hselv[QB];
    __shared__ int   iselv[QB];
    __shared__ int   doneQ[QB];
    __shared__ int   anyleft;
    __shared__ unsigned int wtot[4];
    __shared__ int s_b;
    __shared__ unsigned int s_tot;
    __shared__ float qsh[QB][4];
    __shared__ float redbuf[4][QB * 4];
    const int tid = threadIdx.x, lane = tid & 63, wid = tid >> 6;
    const int qbase = blockIdx.x * QB;

    if (tid < QB) {
        const int qid = qbase + tid;
        float a = 0.f, b = 0.f, c = 0.f;
        if (qid < B) { a = z[qid * 6 + 0]; b = z[qid * 6 + 1]; c = z[qid * 6 + 2]; }
        qsh[tid][0] = a; qsh[tid][1] = b; qsh[tid][2] = c;
        qsh[tid][3] = fmaf(a, a, fmaf(b, b, c * c));
    }
    for (int i = tid; i < QB * NBUCKET; i += KT) (&hist[0][0])[i] = 0u;
    __syncthreads();
    float qx[QB], qy[QB], qz[QB], q2[QB];
#pragma unroll
    for (int q = 0; q < QB; ++q) { qx[q] = qsh[q][0]; qy[q] = qsh[q][1]; qz[q] = qsh[q][2]; q2[q] = qsh[q][3]; }

    auto doPoint = [&](float px, float py, float pz, int idx, auto&& fn) {
        const float p2 = fmaf(px, px, fmaf(py, py, pz * pz));
#pragma unroll
        for (int q = 0; q < QB; ++q) {
            const float dt = fmaf(qx[q], px, fmaf(qy[q], py, qz[q] * pz));
            const float d2 = fmaf(-2.f, dt, q2[q] + p2);
            fn(q, idx, d2);
        }
    };
    auto sweepAll = [&](auto&& fn) {
        const int G0 = N0 >> 2;
        for (int g = tid; g < G0; g += KT) {
            const float4* bp = (const float4*)(x0 + 12 * (size_t)g);
            const float4 A = bp[0], Bv = bp[1], C = bp[2];
            doPoint(A.x, A.y, A.z, 4 * g + 0, fn);
            doPoint(A.w, Bv.x, Bv.y, 4 * g + 1, fn);
            doPoint(Bv.z, Bv.w, C.x, 4 * g + 2, fn);
            doPoint(C.y, C.z, C.w, 4 * g + 3, fn);
        }
        for (int j = (G0 << 2) + tid; j < N0; j += KT)
            doPoint(x0[3 * j], x0[3 * j + 1], x0[3 * j + 2], j, fn);
        const int G1 = N1 >> 2;
        for (int g = tid; g < G1; g += KT) {
            const float4* bp = (const float4*)(x1 + 12 * (size_t)g);
            const float4 A = bp[0], Bv = bp[1], C = bp[2];
            doPoint(A.x, A.y, A.z, N0 + 4 * g + 0, fn);
            doPoint(A.w, Bv.x, Bv.y, N0 + 4 * g + 1, fn);
            doPoint(Bv.z, Bv.w, C.x, N0 + 4 * g + 2, fn);
            doPoint(C.y, C.z, C.w, N0 + 4 * g + 3, fn);
        }
        for (int j = (G1 << 2) + tid; j < N1; j += KT)
            doPoint(x1[3 * j], x1[3 * j + 1], x1[3 * j + 2], N0 + j, fn);
    };

    for (int s = tid; s < 2048; s += KT) {
        const int j = (int)(((long long)s * (long long)N) >> 11);
        float px, py, pz;
        if (j < N0) { px = x0[3 * j]; py = x0[3 * j + 1]; pz = x0[3 * j + 2]; }
        else { const int j2 = j - N0; px = x1[3 * j2]; py = x1[3 * j2 + 1]; pz = x1[3 * j2 + 2]; }
        const float p2 = fmaf(px, px, fmaf(py, py, pz * pz));
#pragma unroll
        for (int q = 0; q < QB; ++q) {
            const float dt = fmaf(qx[q], px, fmaf(qy[q], py, qz[q] * pz));
            float d2 = fmaf(-2.f, dt, q2[q] + p2);
            d2 = fmaxf(d2, 0.f);
            int bu = (int)(__float_as_uint(d2) >> 20);
            bu = bu < (NBUCKET - 1) ? bu : (NBUCKET - 1);
            atomicAdd(&hist[q][bu], 1u);
        }
    }
    __syncthreads();
    for (int q = 0; q < QB; ++q) {
        scan_find<NBUCKET>(&hist[q][0], TSAMP_FB, &s_b, &s_tot, wtot, tid);
        if (tid == 0) {
            int b = s_b; if (b < 0) b = NBUCKET - 1;
            const unsigned int ub = (unsigned int)(b + 1);
            const float cap = (ub >= 2040u) ? 3.4e38f : __uint_as_float(ub << 20);
            capv[q] = (qbase + q < B) ? cap : -1.f;
            doneQ[q] = (qbase + q < B) ? 0 : 1;
        }
        __syncthreads();
    }
    for (int attempt = 0; attempt < 4; ++attempt) {
        if (tid == 0) anyleft = 0;
        if (tid < QB && !doneQ[tid]) candCnt[tid] = 0u;
        __syncthreads();
        float rcap[QB];
#pragma unroll
        for (int q = 0; q < QB; ++q) rcap[q] = doneQ[q] ? -1.f : capv[q];
        sweepAll([&](int q, int j, float d2) {
            if (d2 < rcap[q]) {
                const unsigned int pos = atomicAdd(&candCnt[q], 1u);
                if (pos < (unsigned int)CANDMAX) { candD[q][pos] = sqrtf(fmaxf(d2, 0.f)); candI[q][pos] = j; }
            }
        });
        __syncthreads();
        if (tid < QB && !doneQ[tid]) {
            const unsigned int c = candCnt[tid];
            if (c >= K && c <= (unsigned int)CANDMAX) doneQ[tid] = 1;
            else {
                const unsigned int cc = c < 8u ? 8u : c;
                capv[tid] *= __powf(384.f / (float)cc, 0.6666667f);
                anyleft = 1;
            }
        }
        __syncthreads();
        if (!anyleft) break;
    }
    for (int q = 0; q < QB; ++q) {
        if (qbase + q >= B) continue;
        const unsigned int cnt = candCnt[q];
        const int m = (int)(cnt < (unsigned int)CANDMAX ? cnt : (unsigned int)CANDMAX);
        fh[tid] = 0u;
        __syncthreads();
        const float sc = 256.f / sqrtf(capv[q]);
        for (int i = tid; i < m; i += KT) {
            int b = (int)(candD[q][i] * sc); b = b < 255 ? b : 255;
            atomicAdd(&fh[b], 1u);
        }
        __syncthreads();
        scan_find<256>(fh, K, &s_b, &s_tot, wtot, tid);
        const int bsel = s_b < 0 ? 255 : s_b;
        unsigned int v = (tid < bsel) ? fh[tid] : 0u;
        v = wredu(v);
        if (lane == 0) wtot[wid] = v;
        if (tid == 0) tcnt = 0u;
        __syncthreads();
        const unsigned int Cb = wtot[0] + wtot[1] + wtot[2] + wtot[3];
        for (int i = tid; i < m; i += KT) {
            int b = (int)(candD[q][i] * sc); b = b < 255 ? b : 255;
            if (b == bsel) {
                const unsigned int p = atomicAdd(&tcnt, 1u);
                if (p < (unsigned int)TINY) { tinyD[p] = candD[q][i]; tinyI[p] = candI[q][i]; }
            }
        }
        __syncthreads();
        const int c2 = (int)tcnt;
        const int need = (int)K - 1 - (int)Cb;
        if (c2 <= TINY) {
            for (int i = tid; i < c2; i += KT) {
                const float di = tinyD[i]; const int ii = tinyI[i];
                int r = 0;
                for (int j2 = 0; j2 < c2; ++j2) {
                    const float dj = tinyD[j2];
                    if (dj < di || (dj == di && tinyI[j2] < ii)) ++r;
                }
                if (r == need) { hselv[q] = di; iselv[q] = ii; }
            }
        } else {
            for (int i = tid; i < m; i += KT) {
                const float di = candD[q][i]; const int ii = candI[q][i];
                int r = 0;
                for (int j2 = 0; j2 < m; ++j2) {
                    const float dj = candD[q][j2];
                    if (dj < di || (dj == di && candI[q][j2] < ii)) ++r;
                }
                if (r == (int)K - 1) { hselv[q] = di; iselv[q] = ii; }
            }
        }
        __syncthreads();
    }
    for (int q = 0; q < QB; ++q) {
        if (qbase + q >= B) continue;
        const float hS = hselv[q];
        const int iS = iselv[q];
        const float hcl = fmaxf(hS, EPS_KNN);
        const float inv2h2 = 1.f / (2.f * hcl * hcl);
        const unsigned int cnt = candCnt[q];
        const int m = (int)(cnt < (unsigned int)CANDMAX ? cnt : (unsigned int)CANDMAX);
        float ws = 0.f, ax = 0.f, ay = 0.f, az = 0.f;
        for (int i = tid; i < m; i += KT) {
            const float s = candD[q][i];
            const int j = candI[q][i];
            if (s < hS || (s == hS && j <= iS)) {
                const float w = expf(-(s * s) * inv2h2);
                const float* vp = (j < N0) ? (v0 + 3 * (size_t)j) : (v1 + 3 * (size_t)(j - N0));
                ws += w; ax = fmaf(w, vp[0], ax); ay = fmaf(w, vp[1], ay); az = fmaf(w, vp[2], az);
            }
        }
        ws = wredf(ws); ax = wredf(ax); ay = wredf(ay); az = wredf(az);
        if (lane == 0) {
            redbuf[wid][q * 4 + 0] = ws; redbuf[wid][q * 4 + 1] = ax;
            redbuf[wid][q * 4 + 2] = ay; redbuf[wid][q * 4 + 3] = az;
        }
    }
    __syncthreads();
    if (tid < QB) {
        const int q = tid, qid = qbase + q;
        if (qid < B) {
            const float ws = redbuf[0][q*4+0] + redbuf[1][q*4+0] + redbuf[2][q*4+0] + redbuf[3][q*4+0];
            const float ax = redbuf[0][q*4+1] + redbuf[1][q*4+1] + redbuf[2][q*4+1] + redbuf[3][q*4+1];
            const float ay = redbuf[0][q*4+2] + redbuf[1][q*4+2] + redbuf[2][q*4+2] + redbuf[3][q*4+2];
            const float az = redbuf[0][q*4+3] + redbuf[1][q*4+3] + redbuf[2][q*4+3] + redbuf[3][q*4+3];
            const float inv = 1.f / (ws + EPS_KNN);
            const float ux = ax * inv, uy = ay * inv, uz = az * inv;
            const float d0 = xdot[qid * 3 + 0], d1 = xdot[qid * 3 + 1], d2v = xdot[qid * 3 + 2];
            const float nu = fmaxf(sqrtf(ux * ux + uy * uy + uz * uz), EPS_COS);
            const float nd = fmaxf(sqrtf(d0 * d0 + d1 * d1 + d2v * d2v), EPS_COS);
            const float cs = 1.f - (ux * d0 + uy * d1 + uz * d2v) / (nu * nd);
            const float ex = ux - d0, ey = uy - d1, ez = uz - d2v;
            const float l2 = ex * ex + ey * ey + ez * ez;
            out[qid * 6 + 0] = d0; out[qid * 6 + 1] = d1; out[qid * 6 + 2] = d2v;
            out[qid * 6 + 3] = cs; out[qid * 6 + 4] = cs; out[qid * 6 + 5] = l2;
        }
    }
}

extern "C" void kernel_launch(void* const* d_in, const int* in_sizes, int n_in,
                              void* d_out, int out_size, void* d_ws, size_t ws_size,
                              hipStream_t stream)
{
    const float* z  = (const float*)d_in[0];
    const float* tp = (const float*)d_in[1];
    const float* x0 = (const float*)d_in[2];
    const float* x1 = (const float*)d_in[3];
    const float* v0 = (const float*)d_in[4];
    const float* v1 = (const float*)d_in[5];
    const float* W1 = (const float*)d_in[6];
    const float* b1 = (const float*)d_in[7];
    const float* W2 = (const float*)d_in[8];
    const float* b2 = (const float*)d_in[9];
    const float* W3 = (const float*)d_in[10];
    const float* b3 = (const float*)d_in[11];
    const int*   kp = (const int*)d_in[12];
    float* outp = (float*)d_out;
    const int B  = in_sizes[0] / 6;
    const int N0 = in_sizes[2] / 3;
    const int N1 = in_sizes[3] / 3;
    const int N  = N0 + N1;

    // fixed ws layout head
    size_t off = 0;
    auto alloc = [&](size_t bytes) { size_t o = off; off = (off + bytes + 255) & ~(size_t)255; return o; };
    const size_t o_xdot = alloc((size_t)B * 3 * sizeof(float));
    const size_t o_pts  = alloc((size_t)N * sizeof(float4));
    const size_t o_cap  = alloc((size_t)B * sizeof(float));
    const size_t o_cnt  = alloc((size_t)B * sizeof(unsigned int));
    // adaptive candidate capacity from remaining ws
    int candpq = 0;
    if (ws_size > off + 512) {
        const size_t rem = ws_size - off - 512;
        const size_t per_q = rem / ((size_t)B * 8);
        if (per_q >= 2048) candpq = 2048;
        else if (per_q >= 1024) candpq = 1024;
    }
    const size_t o_gD = alloc((size_t)B * (candpq > 0 ? candpq : 1) * sizeof(float));
    const size_t o_gI = alloc((size_t)B * (candpq > 0 ? candpq : 1) * sizeof(int));
    const bool split = (candpq > 0) && (ws_size >= off);
    const unsigned int ts = (candpq >= 2048) ? 16u : 8u;

    float* xdot = (float*)((char*)d_ws + o_xdot);

    hipLaunchKernelGGL(mlp_kernel, dim3((B + MQ - 1) / MQ), dim3(512), 0, stream,
                       z, tp, W1, b1, W2, b2, W3, b3, xdot, B);
    if (split) {
        float4* pts = (float4*)((char*)d_ws + o_pts);
        float* capg = (float*)((char*)d_ws + o_cap);
        unsigned int* gcnt = (unsigned int*)((char*)d_ws + o_cnt);
        float* gD = (float*)((char*)d_ws + o_gD);
        int*   gI = (int*)((char*)d_ws + o_gI);
        const int QG = (B + QA - 1) / QA;
        hipLaunchKernelGGL(pack_kernel, dim3((N + 255) / 256), dim3(256), 0, stream,
                           x0, x1, pts, N0, N);
        hipLaunchKernelGGL(sample_kernel, dim3(B), dim3(KT), 0, stream,
                           z, pts, capg, gcnt, B, N, ts);
        hipLaunchKernelGGL(sweepA_kernel, dim3(QG * SLICES), dim3(KT), 0, stream,
                           z, pts, capg, gcnt, gD, gI, B, N, candpq);
        hipLaunchKernelGGL(finalB_kernel, dim3((B + QBF - 1) / QBF), dim3(KT), 0, stream,
                           z, pts, v0, v1, xdot, kp, capg, gcnt, gD, gI, outp, B, N0, N1, candpq);
    } else {
        hipLaunchKernelGGL(knn_fallback, dim3((B + QB - 1) / QB), dim3(KT), 0, stream,
                           z, x0, x1, v0, v1, xdot, kp, outp, B, N0, N1);
    }
}